// Round 1
// baseline (305.019 us; speedup 1.0000x reference)
//
#include <hip/hip_runtime.h>
#include <hip/hip_bf16.h>
#include <cstdint>

typedef unsigned short u16;
typedef unsigned int   u32;

typedef __attribute__((ext_vector_type(8))) short short8;   // 8 x bf16 (4 VGPRs)
typedef __attribute__((ext_vector_type(4))) float f32x4;    // MFMA accumulator

__device__ __forceinline__ float b2f(u16 v) { return __uint_as_float(((u32)v) << 16); }
__device__ __forceinline__ u16 f2b(float f) {
    u32 u = __float_as_uint(f);
    u += 0x7FFFu + ((u >> 16) & 1u);   // round-to-nearest-even
    return (u16)(u >> 16);
}

#define G2L16(gp, lp) __builtin_amdgcn_global_load_lds(                       \
    (const __attribute__((address_space(1))) void*)(gp),                      \
    (__attribute__((address_space(3))) void*)(lp), 16, 0, 0)

// ---------------------------------------------------------------------------
// Fused prologue (unchanged): transposes, iQ cast, iV chunk sums.
// ---------------------------------------------------------------------------
__device__ __forceinline__ void transpose_body(const float* __restrict__ in,
                                               u16* __restrict__ out,
                                               int R, int C, int lb, int tilesX,
                                               float (*tile)[33]) {
    const int bx = (lb % tilesX) * 32;
    const int by = (lb / tilesX) * 32;
    const int tx = threadIdx.x & 31, ty = threadIdx.x >> 5;   // 32 x 8
    #pragma unroll
    for (int i = 0; i < 32; i += 8)
        tile[ty + i][tx] = in[(size_t)(by + ty + i) * C + (bx + tx)];
    __syncthreads();
    #pragma unroll
    for (int i = 0; i < 32; i += 8)
        out[(size_t)(bx + ty + i) * R + (by + tx)] = f2b(tile[tx][ty + i]);
}

__global__ void prologue_kernel(const float* __restrict__ W1, u16* __restrict__ W1t,
                                const float* __restrict__ W2, u16* __restrict__ W2t,
                                const float* __restrict__ Wg, u16* __restrict__ Wgt,
                                const float* __restrict__ iQ, u16* __restrict__ iQb,
                                const float* __restrict__ iV, float* __restrict__ csum) {
    __shared__ float tile[32][33];
    const int bid = blockIdx.x;
    const int tid = threadIdx.x;
    if (bid < 1024) {
        transpose_body(W1, W1t, 1024, 1024, bid, 32, tile);
    } else if (bid < 2048) {
        transpose_body(W2, W2t, 1024, 1024, bid - 1024, 32, tile);
    } else if (bid < 6144) {
        transpose_body(Wg, Wgt, 2048, 2048, bid - 2048, 64, tile);
    } else if (bid < 14336) {
        const size_t i = ((size_t)(bid - 6144) * 256 + tid) * 4;
        const float4 v = *(const float4*)(iQ + i);
        ushort4 o;
        o.x = f2b(v.x); o.y = f2b(v.y); o.z = f2b(v.z); o.w = f2b(v.w);
        *(ushort4*)(iQb + i) = o;
    } else {
        const int idx = bid - 14336;
        const int b = idx >> 6, c = idx & 63;
        const int d = tid * 4;
        const float* src = iV + ((size_t)(b * 2048 + c * 32)) * 1024 + d;
        float4 s = {0.f, 0.f, 0.f, 0.f};
        #pragma unroll 8
        for (int i = 0; i < 32; ++i) {
            const float4 v = *(const float4*)(src + (size_t)i * 1024);
            s.x += v.x; s.y += v.y; s.z += v.z; s.w += v.w;
        }
        *(float4*)(csum + ((size_t)(b * 64 + c)) * 1024 + d) = s;
    }
}

// ---------------------------------------------------------------------------
// Scan (unchanged): prefix over chunk sums + in-chunk serial scan -> avg bf16.
// ---------------------------------------------------------------------------
__global__ void scan_kernel(const float* __restrict__ iV, const float* __restrict__ csum,
                            u16* __restrict__ avg) {
    const int c = blockIdx.x & 63, b = blockIdx.x >> 6;
    const int d = threadIdx.x * 4;
    const float* cs = csum + (size_t)b * 64 * 1024 + d;
    float4 a0 = {0,0,0,0}, a1 = {0,0,0,0}, a2 = {0,0,0,0}, a3 = {0,0,0,0};
    int cc = 0;
    for (; cc + 4 <= c; cc += 4) {
        const float4 v0 = *(const float4*)(cs + (size_t)(cc + 0) * 1024);
        const float4 v1 = *(const float4*)(cs + (size_t)(cc + 1) * 1024);
        const float4 v2 = *(const float4*)(cs + (size_t)(cc + 2) * 1024);
        const float4 v3 = *(const float4*)(cs + (size_t)(cc + 3) * 1024);
        a0.x += v0.x; a0.y += v0.y; a0.z += v0.z; a0.w += v0.w;
        a1.x += v1.x; a1.y += v1.y; a1.z += v1.z; a1.w += v1.w;
        a2.x += v2.x; a2.y += v2.y; a2.z += v2.z; a2.w += v2.w;
        a3.x += v3.x; a3.y += v3.y; a3.z += v3.z; a3.w += v3.w;
    }
    for (; cc < c; ++cc) {
        const float4 v = *(const float4*)(cs + (size_t)cc * 1024);
        a0.x += v.x; a0.y += v.y; a0.z += v.z; a0.w += v.w;
    }
    float4 acc;
    acc.x = (a0.x + a1.x) + (a2.x + a3.x);
    acc.y = (a0.y + a1.y) + (a2.y + a3.y);
    acc.z = (a0.z + a1.z) + (a2.z + a3.z);
    acc.w = (a0.w + a1.w) + (a2.w + a3.w);

    const size_t off = ((size_t)(b * 2048 + c * 32)) * 1024 + d;
    const float* src = iV + off;
    u16*         dst = avg + off;
    const int s0 = c * 32;
    #pragma unroll 4
    for (int i = 0; i < 32; ++i) {
        const float4 v = *(const float4*)(src + (size_t)i * 1024);
        acc.x += v.x; acc.y += v.y; acc.z += v.z; acc.w += v.w;
        const float inv = 1.0f / (float)(s0 + i + 1);
        ushort4 o;
        o.x = f2b(acc.x * inv); o.y = f2b(acc.y * inv);
        o.z = f2b(acc.z * inv); o.w = f2b(acc.w * inv);
        *(ushort4*)(dst + (size_t)i * 1024) = o;
    }
}

// ---------------------------------------------------------------------------
// Pipelined 256x128 GEMM (T2+T3+T4+T5): double-buffered LDS, counted vmcnt
// (prefetch tile t+2 stays in flight across the barrier; never drain to 0 in
// steady state), raw s_barrier + sched_barrier(0) fences, setprio around MFMA.
//   MODE 0: C = relu(A@Bt^T + bias)            (bf16 out)
//   MODE 1: C = A@Bt^T + bias                  (bf16 out)
//   MODE 2: gate: A=concat(iQb,ffn) rows, Bt=Wgt (2048x2048); per-wave both
//           column halves -> fused sigmoid-gate epilogue, f32 out.
// Geometry: 512 thr / 8 waves; wave = 128 rows x 32 cols; acc[8][2](x2 halves).
// LDS swizzle: row r (128B), 16B chunk q stored at slot q^(r&7) (proven 0-conflict).
// ---------------------------------------------------------------------------
template <int MODE>
__global__ __launch_bounds__(512, 2)
void gemm_pipe_kernel(const u16* __restrict__ A, const u16* __restrict__ A2,
                      const u16* __restrict__ Bt, const float* __restrict__ bias,
                      u16* __restrict__ Cb, const float* __restrict__ iQ,
                      float* __restrict__ out) {
    constexpr int NT  = (MODE == 2) ? 32 : 16;       // K tiles of 64
    constexpr int KBB = ((MODE == 2) ? 2048 : 1024) * 2; // B row stride, bytes
    constexpr int VPT = (MODE == 2) ? 8 : 6;         // global_load_lds per tile/thread

    __shared__ u16 As[2][256 * 64];
    __shared__ u16 Bs[2][(MODE == 2 ? 2 : 1) * 128 * 64];

    const int tid   = threadIdx.x;
    const int m0    = (blockIdx.x >> 3) * 256;
    const int n0    = (blockIdx.x & 7) * 128;        // n_tile == XCD id under %8 rr
    const int wave  = tid >> 6, lane = tid & 63;
    const int wm128 = (wave & 1) << 7;
    const int wn32  = (wave >> 1) << 5;
    const int quad  = lane >> 4, l16 = lane & 15;

    // staging descriptors (byte offsets; all fit u32)
    u32 oA[4], gA[4];
    #pragma unroll
    for (int j = 0; j < 4; ++j) {
        const u32 o = tid * 16 + j * 8192;           // 32KB A tile
        const u32 r = o >> 7;
        const u32 q = ((o >> 4) & 7) ^ (r & 7);
        oA[j] = o;
        gA[j] = (u32)(m0 + r) * 2048 + q * 16;       // A row stride 1024 u16
    }
    u32 oB[2], gB0[2], gB1[2];
    #pragma unroll
    for (int j = 0; j < 2; ++j) {
        const u32 o = tid * 16 + j * 8192;           // 16KB per B half
        const u32 r = o >> 7;
        const u32 q = ((o >> 4) & 7) ^ (r & 7);
        oB[j] = o;
        gB0[j] = (u32)(n0 + r) * KBB + q * 16;
        if (MODE == 2) gB1[j] = (u32)(n0 + 1024 + r) * KBB + q * 16;
    }

    f32x4 acc0[8][2];
    f32x4 acc1[(MODE == 2) ? 8 : 1][2];
    #pragma unroll
    for (int mi = 0; mi < 8; ++mi)
        #pragma unroll
        for (int ni = 0; ni < 2; ++ni) {
            acc0[mi][ni] = (f32x4){0.f, 0.f, 0.f, 0.f};
            if constexpr (MODE == 2) acc1[mi][ni] = (f32x4){0.f, 0.f, 0.f, 0.f};
        }

    auto stage = [&](int b, int t) {
        const int kb2 = t << 7;                       // t*64 elems * 2B
        const char* Ab;
        if constexpr (MODE == 2)
            Ab = (t < 16) ? ((const char*)A + kb2) : ((const char*)A2 + (kb2 - 2048));
        else
            Ab = (const char*)A + kb2;
        #pragma unroll
        for (int j = 0; j < 4; ++j)
            G2L16(Ab + gA[j], (char*)&As[b][0] + oA[j]);
        #pragma unroll
        for (int j = 0; j < 2; ++j)
            G2L16((const char*)Bt + kb2 + gB0[j], (char*)&Bs[b][0] + oB[j]);
        if constexpr (MODE == 2) {
            #pragma unroll
            for (int j = 0; j < 2; ++j)
                G2L16((const char*)Bt + kb2 + gB1[j], (char*)&Bs[b][128 * 64] + oB[j]);
        }
    };

    auto compute = [&](int b) {
        const u16* Asb = &As[b][0];
        const u16* B0b = &Bs[b][0];
        const u16* B1b = &Bs[b][(MODE == 2 ? 128 * 64 : 0)];
        #pragma unroll
        for (int h = 0; h < 2; ++h) {                 // two K=32 half-phases
            const int h4 = h << 2;
            short8 af[8], b0f[2], b1f[2];
            #pragma unroll
            for (int mi = 0; mi < 8; ++mi) {
                const int R = wm128 + mi * 16 + l16;
                af[mi] = *(const short8*)(Asb + R * 64 + (((h4 | quad) ^ (R & 7)) << 3));
            }
            #pragma unroll
            for (int ni = 0; ni < 2; ++ni) {
                const int R = wn32 + ni * 16 + l16;
                const int so = R * 64 + (((h4 | quad) ^ (R & 7)) << 3);
                b0f[ni] = *(const short8*)(B0b + so);
                if constexpr (MODE == 2) b1f[ni] = *(const short8*)(B1b + so);
            }
            __builtin_amdgcn_s_setprio(1);
            #pragma unroll
            for (int mi = 0; mi < 8; ++mi)
                #pragma unroll
                for (int ni = 0; ni < 2; ++ni) {
                    acc0[mi][ni] = __builtin_amdgcn_mfma_f32_16x16x32_bf16(
                        af[mi], b0f[ni], acc0[mi][ni], 0, 0, 0);
                    if constexpr (MODE == 2)
                        acc1[mi][ni] = __builtin_amdgcn_mfma_f32_16x16x32_bf16(
                            af[mi], b1f[ni], acc1[mi][ni], 0, 0, 0);
                }
            __builtin_amdgcn_s_setprio(0);
        }
    };

    // prologue: tiles 0,1 staged; wait tile 0 only (tile 1 stays in flight)
    stage(0, 0);
    stage(1, 1);
    asm volatile("s_waitcnt vmcnt(%0)" :: "i"(VPT) : "memory");
    __builtin_amdgcn_s_barrier();
    __builtin_amdgcn_sched_barrier(0);

    for (int t = 0; t < NT; ++t) {
        const int cur = t & 1;
        compute(cur);
        __builtin_amdgcn_sched_barrier(0);
        __builtin_amdgcn_s_barrier();                 // all waves done reading buf[cur]
        __builtin_amdgcn_sched_barrier(0);
        if (t + 2 < NT) {
            stage(cur, t + 2);                        // overwrite consumed buffer
            asm volatile("s_waitcnt vmcnt(%0)" :: "i"(VPT) : "memory");  // t+1 landed
        } else if (t + 2 == NT) {
            asm volatile("s_waitcnt vmcnt(0)" ::: "memory");             // tail drain
        }
        __builtin_amdgcn_s_barrier();                 // buf[cur^1] now valid for all
        __builtin_amdgcn_sched_barrier(0);
    }

    if constexpr (MODE == 2) {
        #pragma unroll
        for (int ni = 0; ni < 2; ++ni) {
            const int col = n0 + wn32 + ni * 16 + l16;
            const float bgi = bias[col];
            const float bgf = bias[col + 1024];
            #pragma unroll
            for (int mi = 0; mi < 8; ++mi) {
                const int row0 = m0 + wm128 + mi * 16 + (quad << 2);
                #pragma unroll
                for (int r = 0; r < 4; ++r) {
                    const size_t idx = (size_t)(row0 + r) * 1024 + col;
                    const float gi = 1.0f / (1.0f + __expf(-(acc0[mi][ni][r] + bgi)));
                    const float gf = 1.0f / (1.0f + __expf(-(acc1[mi][ni][r] + bgf)));
                    out[idx] = gi * iQ[idx] + gf * b2f(A2[idx]);
                }
            }
        }
    } else {
        #pragma unroll
        for (int ni = 0; ni < 2; ++ni) {
            const int col = n0 + wn32 + ni * 16 + l16;
            const float bv = bias[col];
            #pragma unroll
            for (int mi = 0; mi < 8; ++mi) {
                const int row0 = m0 + wm128 + mi * 16 + (quad << 2);
                #pragma unroll
                for (int r = 0; r < 4; ++r) {
                    float v = acc0[mi][ni][r] + bv;
                    if (MODE == 0) v = fmaxf(v, 0.f);
                    Cb[(size_t)(row0 + r) * 1024 + col] = f2b(v);
                }
            }
        }
    }
}

// ---------------------------------------------------------------------------
extern "C" void kernel_launch(void* const* d_in, const int* in_sizes, int n_in,
                              void* d_out, int out_size, void* d_ws, size_t ws_size,
                              hipStream_t stream) {
    const int B = 4, S = 2048, D = 1024, D2 = 2048;
    const int M = B * S;  // 8192

    const float* iQ = (const float*)d_in[0];
    const float* iV = (const float*)d_in[1];
    const float* W1 = (const float*)d_in[2];
    const float* b1 = (const float*)d_in[3];
    const float* W2 = (const float*)d_in[4];
    const float* b2 = (const float*)d_in[5];
    const float* Wg = (const float*)d_in[6];
    const float* bg = (const float*)d_in[7];
    float* out = (float*)d_out;

    // workspace, no aliasing (61 MB):
    u16*   regA = (u16*)d_ws;                    // avg -> ffn   (16 MB)
    u16*   regB = regA + (size_t)M * D;          // h            (16 MB)
    u16*   iQb  = regB + (size_t)M * D;          // iQ bf16      (16 MB)
    u16*   W1t  = iQb  + (size_t)M * D;          //              ( 2 MB)
    u16*   W2t  = W1t  + (size_t)D * D;          //              ( 2 MB)
    u16*   Wgt  = W2t  + (size_t)D * D;          //              ( 8 MB)
    float* csum = (float*)(Wgt + (size_t)D2 * D2); // B*64*D f32 ( 1 MB)

    u16* avg = regA;
    u16* ffn = regA;
    u16* h   = regB;

    // 1. all independent prologue work in one big dispatch (14592 blocks)
    prologue_kernel<<<14592, 256, 0, stream>>>(W1, W1t, W2, W2t, Wg, Wgt,
                                               iQ, iQb, iV, csum);
    // 2. causal cumulative mean
    scan_kernel<<<B * 64, 256, 0, stream>>>(iV, csum, avg);
    // 3. h = relu(avg @ W1 + b1)
    gemm_pipe_kernel<0><<<256, 512, 0, stream>>>(avg, nullptr, W1t, b1, h, nullptr, nullptr);
    // 4. ffn = h @ W2 + b2   (overlays avg)
    gemm_pipe_kernel<1><<<256, 512, 0, stream>>>(h, nullptr, W2t, b2, ffn, nullptr, nullptr);
    // 5. fused gate GEMM + sigmoid-gate epilogue
    gemm_pipe_kernel<2><<<256, 512, 0, stream>>>(iQb, ffn, Wgt, bg, nullptr, iQ, out);
}

// Round 2
// 284.360 us; speedup vs baseline: 1.0727x; 1.0727x over previous
//
#include <hip/hip_runtime.h>
#include <hip/hip_bf16.h>
#include <cstdint>

typedef unsigned short u16;
typedef unsigned int   u32;

typedef __attribute__((ext_vector_type(8))) short short8;   // 8 x bf16 (4 VGPRs)
typedef __attribute__((ext_vector_type(4))) float f32x4;    // MFMA accumulator

__device__ __forceinline__ float b2f(u16 v) { return __uint_as_float(((u32)v) << 16); }
__device__ __forceinline__ u16 f2b(float f) {
    u32 u = __float_as_uint(f);
    u += 0x7FFFu + ((u >> 16) & 1u);   // round-to-nearest-even
    return (u16)(u >> 16);
}

#define G2L16(gp, lp) __builtin_amdgcn_global_load_lds(                       \
    (const __attribute__((address_space(1))) void*)(gp),                      \
    (__attribute__((address_space(3))) void*)(lp), 16, 0, 0)

// ---------------------------------------------------------------------------
// Fused prologue (unchanged): transposes, iQ cast, iV chunk sums.
// ---------------------------------------------------------------------------
__device__ __forceinline__ void transpose_body(const float* __restrict__ in,
                                               u16* __restrict__ out,
                                               int R, int C, int lb, int tilesX,
                                               float (*tile)[33]) {
    const int bx = (lb % tilesX) * 32;
    const int by = (lb / tilesX) * 32;
    const int tx = threadIdx.x & 31, ty = threadIdx.x >> 5;   // 32 x 8
    #pragma unroll
    for (int i = 0; i < 32; i += 8)
        tile[ty + i][tx] = in[(size_t)(by + ty + i) * C + (bx + tx)];
    __syncthreads();
    #pragma unroll
    for (int i = 0; i < 32; i += 8)
        out[(size_t)(bx + ty + i) * R + (by + tx)] = f2b(tile[tx][ty + i]);
}

__global__ void prologue_kernel(const float* __restrict__ W1, u16* __restrict__ W1t,
                                const float* __restrict__ W2, u16* __restrict__ W2t,
                                const float* __restrict__ Wg, u16* __restrict__ Wgt,
                                const float* __restrict__ iQ, u16* __restrict__ iQb,
                                const float* __restrict__ iV, float* __restrict__ csum) {
    __shared__ float tile[32][33];
    const int bid = blockIdx.x;
    const int tid = threadIdx.x;
    if (bid < 1024) {
        transpose_body(W1, W1t, 1024, 1024, bid, 32, tile);
    } else if (bid < 2048) {
        transpose_body(W2, W2t, 1024, 1024, bid - 1024, 32, tile);
    } else if (bid < 6144) {
        transpose_body(Wg, Wgt, 2048, 2048, bid - 2048, 64, tile);
    } else if (bid < 14336) {
        const size_t i = ((size_t)(bid - 6144) * 256 + tid) * 4;
        const float4 v = *(const float4*)(iQ + i);
        ushort4 o;
        o.x = f2b(v.x); o.y = f2b(v.y); o.z = f2b(v.z); o.w = f2b(v.w);
        *(ushort4*)(iQb + i) = o;
    } else {
        const int idx = bid - 14336;
        const int b = idx >> 6, c = idx & 63;
        const int d = tid * 4;
        const float* src = iV + ((size_t)(b * 2048 + c * 32)) * 1024 + d;
        float4 s = {0.f, 0.f, 0.f, 0.f};
        #pragma unroll 8
        for (int i = 0; i < 32; ++i) {
            const float4 v = *(const float4*)(src + (size_t)i * 1024);
            s.x += v.x; s.y += v.y; s.z += v.z; s.w += v.w;
        }
        *(float4*)(csum + ((size_t)(b * 64 + c)) * 1024 + d) = s;
    }
}

// ---------------------------------------------------------------------------
// Scan (unchanged): prefix over chunk sums + in-chunk serial scan -> avg bf16.
// ---------------------------------------------------------------------------
__global__ void scan_kernel(const float* __restrict__ iV, const float* __restrict__ csum,
                            u16* __restrict__ avg) {
    const int c = blockIdx.x & 63, b = blockIdx.x >> 6;
    const int d = threadIdx.x * 4;
    const float* cs = csum + (size_t)b * 64 * 1024 + d;
    float4 a0 = {0,0,0,0}, a1 = {0,0,0,0}, a2 = {0,0,0,0}, a3 = {0,0,0,0};
    int cc = 0;
    for (; cc + 4 <= c; cc += 4) {
        const float4 v0 = *(const float4*)(cs + (size_t)(cc + 0) * 1024);
        const float4 v1 = *(const float4*)(cs + (size_t)(cc + 1) * 1024);
        const float4 v2 = *(const float4*)(cs + (size_t)(cc + 2) * 1024);
        const float4 v3 = *(const float4*)(cs + (size_t)(cc + 3) * 1024);
        a0.x += v0.x; a0.y += v0.y; a0.z += v0.z; a0.w += v0.w;
        a1.x += v1.x; a1.y += v1.y; a1.z += v1.z; a1.w += v1.w;
        a2.x += v2.x; a2.y += v2.y; a2.z += v2.z; a2.w += v2.w;
        a3.x += v3.x; a3.y += v3.y; a3.z += v3.z; a3.w += v3.w;
    }
    for (; cc < c; ++cc) {
        const float4 v = *(const float4*)(cs + (size_t)cc * 1024);
        a0.x += v.x; a0.y += v.y; a0.z += v.z; a0.w += v.w;
    }
    float4 acc;
    acc.x = (a0.x + a1.x) + (a2.x + a3.x);
    acc.y = (a0.y + a1.y) + (a2.y + a3.y);
    acc.z = (a0.z + a1.z) + (a2.z + a3.z);
    acc.w = (a0.w + a1.w) + (a2.w + a3.w);

    const size_t off = ((size_t)(b * 2048 + c * 32)) * 1024 + d;
    const float* src = iV + off;
    u16*         dst = avg + off;
    const int s0 = c * 32;
    #pragma unroll 4
    for (int i = 0; i < 32; ++i) {
        const float4 v = *(const float4*)(src + (size_t)i * 1024);
        acc.x += v.x; acc.y += v.y; acc.z += v.z; acc.w += v.w;
        const float inv = 1.0f / (float)(s0 + i + 1);
        ushort4 o;
        o.x = f2b(acc.x * inv); o.y = f2b(acc.y * inv);
        o.z = f2b(acc.z * inv); o.w = f2b(acc.w * inv);
        *(ushort4*)(dst + (size_t)i * 1024) = o;
    }
}

// ---------------------------------------------------------------------------
// Round-0 proven MFMA GEMM (948 TF-class), BK=64, XOR-swizzled LDS.
// EPI: 0 = relu(x+b), 1 = x+b.
// ---------------------------------------------------------------------------
template <int EPI>
__global__ __launch_bounds__(256, 2)
void gemm_kernel(const u16* __restrict__ A, const u16* __restrict__ Bt,
                 const float* __restrict__ bias, u16* __restrict__ C,
                 int M, int N, int K) {
    __shared__ u16 As[128 * 64];
    __shared__ u16 Bs[128 * 64];

    const int tid  = threadIdx.x;
    const int m0   = blockIdx.x * 128;
    const int n0   = blockIdx.y * 128;
    const int wave = tid >> 6, lane = tid & 63;
    const int wm   = (wave & 1) << 6;
    const int wn   = (wave >> 1) << 6;
    const int quad = lane >> 4, l16 = lane & 15;

    f32x4 acc[4][4];
    #pragma unroll
    for (int i = 0; i < 4; ++i)
        #pragma unroll
        for (int j = 0; j < 4; ++j) acc[i][j] = (f32x4){0.f, 0.f, 0.f, 0.f};

    int oo[4], rr[4], qq[4];
    #pragma unroll
    for (int j = 0; j < 4; ++j) {
        oo[j] = tid * 16 + j * 4096;
        rr[j] = oo[j] >> 7;
        qq[j] = ((oo[j] >> 4) & 7) ^ (rr[j] & 7);
    }

    const int ktiles = K >> 6;
    for (int kt = 0; kt < ktiles; ++kt) {
        const int kb = kt << 6;
        #pragma unroll
        for (int j = 0; j < 4; ++j) {
            G2L16((const char*)A  + ((size_t)(m0 + rr[j]) * K + kb) * 2 + qq[j] * 16,
                  (char*)As + oo[j]);
            G2L16((const char*)Bt + ((size_t)(n0 + rr[j]) * K + kb) * 2 + qq[j] * 16,
                  (char*)Bs + oo[j]);
        }
        __syncthreads();

        #pragma unroll
        for (int h = 0; h < 2; ++h) {
            short8 af[4], bf[4];
            #pragma unroll
            for (int mi = 0; mi < 4; ++mi) {
                const int R = wm + mi * 16 + l16;
                af[mi] = *(const short8*)(As + R * 64 + ((((h << 2) | quad) ^ (R & 7)) << 3));
            }
            #pragma unroll
            for (int ni = 0; ni < 4; ++ni) {
                const int R = wn + ni * 16 + l16;
                bf[ni] = *(const short8*)(Bs + R * 64 + ((((h << 2) | quad) ^ (R & 7)) << 3));
            }
            #pragma unroll
            for (int mi = 0; mi < 4; ++mi)
                #pragma unroll
                for (int ni = 0; ni < 4; ++ni)
                    acc[mi][ni] = __builtin_amdgcn_mfma_f32_16x16x32_bf16(
                        af[mi], bf[ni], acc[mi][ni], 0, 0, 0);
        }
        __syncthreads();
    }

    #pragma unroll
    for (int ni = 0; ni < 4; ++ni) {
        const int col = n0 + wn + ni * 16 + l16;
        const float bv = bias[col];
        #pragma unroll
        for (int mi = 0; mi < 4; ++mi) {
            const int row0 = m0 + wm + mi * 16 + quad * 4;
            #pragma unroll
            for (int r = 0; r < 4; ++r) {
                float v = acc[mi][ni][r] + bv;
                if (EPI == 0) v = fmaxf(v, 0.f);
                C[(size_t)(row0 + r) * N + col] = f2b(v);
            }
        }
    }
}

// ---------------------------------------------------------------------------
// 8-phase gate GEMM (T2+T3+T4+T5), 256 rows x 128 out-cols, both gate halves.
// A-tile = 256 rows of concat(iQb,ffn) as halves A0/A1 (128x64 each).
// B-tile = Wgt rows [n0,n0+128) (lo=gi) and [n0+1024,+128) (hi=gf).
// 8 waves (wm in {0,1}: rows wm*64.. within each A-half; wn in 0..3: 32 cols).
// Per phase: quadrant (mh,g) = 8 A-frag + 4 B-frag ds_read_b128, 0-2 half-tile
// stages, barrier, lgkmcnt(0), setprio(1), 16 MFMA, setprio(0), barrier.
// Counted vmcnt(4) only at phases 4 and 8; last iteration peeled with vmcnt(0).
// Stage rotation (derived from slot deaths; deadlines verified vs both vmcnts):
//   P1: buf1.A1/Blo (tile t1)   P3: buf0.A0 (t0+2)  P4: buf0.Bhi (t0+2)
//   P5: buf0.Blo+A1 (t0+2)      P7: buf1.A0 (t1+2)  P8: buf1.Bhi (t1+2)
// ---------------------------------------------------------------------------
#define VM4  asm volatile("s_waitcnt vmcnt(4)" ::: "memory")
#define VM0  asm volatile("s_waitcnt vmcnt(0)" ::: "memory")
#define NOVM ((void)0)

#define SA(BUF, MH, T) do {                                                     \
    const char* b_ = ((T) < 16) ? ((const char*)iQb + (size_t)(T) * 128)        \
                                : ((const char*)ffn + (size_t)((T) - 16) * 128); \
    G2L16(b_ + gA[MH][0], (char*)&As[BUF][MH][0] + lo[0]);                      \
    G2L16(b_ + gA[MH][1], (char*)&As[BUF][MH][0] + lo[1]);                      \
  } while (0)

#define SB(BUF, GG, T) do {                                                     \
    const char* b_ = (const char*)Wgt + (size_t)(T) * 128;                      \
    G2L16(b_ + gB[GG][0], (char*)&Bs[BUF][GG][0] + lo[0]);                      \
    G2L16(b_ + gB[GG][1], (char*)&Bs[BUF][GG][0] + lo[1]);                      \
  } while (0)

#define PHASE(BUF, MH, G, STAGES, VMW) do {                                     \
    short8 af[4][2], bf[2][2];                                                  \
    {                                                                           \
      const char* Ab_ = (const char*)&As[BUF][MH][0];                           \
      const char* Bb_ = (const char*)&Bs[BUF][G][0];                            \
      _Pragma("unroll")                                                         \
      for (int mi = 0; mi < 4; ++mi) {                                          \
        af[mi][0] = *(const short8*)(Ab_ + aF[mi][0]);                          \
        af[mi][1] = *(const short8*)(Ab_ + aF[mi][1]);                          \
      }                                                                         \
      bf[0][0] = *(const short8*)(Bb_ + bF[0][0]);                              \
      bf[0][1] = *(const short8*)(Bb_ + bF[0][1]);                              \
      bf[1][0] = *(const short8*)(Bb_ + bF[1][0]);                              \
      bf[1][1] = *(const short8*)(Bb_ + bF[1][1]);                              \
    }                                                                           \
    STAGES                                                                      \
    __builtin_amdgcn_sched_barrier(0);                                          \
    __builtin_amdgcn_s_barrier();                                               \
    asm volatile("s_waitcnt lgkmcnt(0)" ::: "memory");                          \
    __builtin_amdgcn_sched_barrier(0);                                          \
    __builtin_amdgcn_s_setprio(1);                                              \
    _Pragma("unroll")                                                           \
    for (int mi = 0; mi < 4; ++mi) {                                            \
      _Pragma("unroll")                                                         \
      for (int ni = 0; ni < 2; ++ni) {                                          \
        acc[G][(MH) * 4 + mi][ni] = __builtin_amdgcn_mfma_f32_16x16x32_bf16(    \
            af[mi][0], bf[ni][0], acc[G][(MH) * 4 + mi][ni], 0, 0, 0);          \
        acc[G][(MH) * 4 + mi][ni] = __builtin_amdgcn_mfma_f32_16x16x32_bf16(    \
            af[mi][1], bf[ni][1], acc[G][(MH) * 4 + mi][ni], 0, 0, 0);          \
      }                                                                         \
    }                                                                           \
    __builtin_amdgcn_s_setprio(0);                                              \
    __builtin_amdgcn_sched_barrier(0);                                          \
    VMW;                                                                        \
    __builtin_amdgcn_s_barrier();                                               \
    __builtin_amdgcn_sched_barrier(0);                                          \
  } while (0)

__global__ __launch_bounds__(512, 2)
void gate8_kernel(const u16* __restrict__ iQb, const u16* __restrict__ ffn,
                  const u16* __restrict__ Wgt, const float* __restrict__ bg,
                  const float* __restrict__ iQ, float* __restrict__ out) {
    __shared__ u16 As[2][2][128 * 64];   // [buf][mh] 16KB half-tiles
    __shared__ u16 Bs[2][2][128 * 64];   // [buf][g]

    const int tid  = threadIdx.x;
    const int bid  = blockIdx.x;
    const int m0   = (bid & 31) * 256;   // m fast-varying: xcd = m_tile % 8
    const int n0   = (bid >> 5) * 128;
    const int wave = tid >> 6, lane = tid & 63;
    const int wm   = wave & 1;
    const int wn   = wave >> 1;
    const int quad = lane >> 4, l16 = lane & 15;

    // staging constants: 2 x global_load_lds(16B) per half-tile per thread
    u32 lo[2], gA[2][2], gB[2][2];
    #pragma unroll
    for (int j = 0; j < 2; ++j) {
        const u32 o = (u32)tid * 16 + (u32)j * 8192;
        const u32 r = o >> 7;
        const u32 q = ((o >> 4) & 7) ^ (r & 7);
        lo[j]    = o;
        gA[0][j] = (u32)(m0 + r) * 2048 + q * 16;          // A row = 2048 B
        gA[1][j] = (u32)(m0 + 128 + r) * 2048 + q * 16;
        gB[0][j] = (u32)(n0 + r) * 4096 + q * 16;          // Wgt row = 4096 B
        gB[1][j] = (u32)(n0 + 1024 + r) * 4096 + q * 16;
    }

    // fragment ds_read byte offsets (swizzle slot = (ks*4+quad)^(R&7))
    u32 aF[4][2], bF[2][2];
    #pragma unroll
    for (int mi = 0; mi < 4; ++mi) {
        const int R = wm * 64 + mi * 16 + l16;
        #pragma unroll
        for (int ks = 0; ks < 2; ++ks)
            aF[mi][ks] = (u32)R * 128 + (u32)((((ks << 2) | quad) ^ (R & 7)) << 4);
    }
    #pragma unroll
    for (int ni = 0; ni < 2; ++ni) {
        const int R = wn * 32 + ni * 16 + l16;
        #pragma unroll
        for (int ks = 0; ks < 2; ++ks)
            bF[ni][ks] = (u32)R * 128 + (u32)((((ks << 2) | quad) ^ (R & 7)) << 4);
    }

    f32x4 acc[2][8][2];
    #pragma unroll
    for (int g = 0; g < 2; ++g)
        #pragma unroll
        for (int mf = 0; mf < 8; ++mf)
            #pragma unroll
            for (int ni = 0; ni < 2; ++ni)
                acc[g][mf][ni] = (f32x4){0.f, 0.f, 0.f, 0.f};

    // prologue: buf0 <- tile0 (all 4 half-tiles, 8 loads), buf1 <- tile1 A0,Bhi
    SA(0, 0, 0); SA(0, 1, 0); SB(0, 0, 0); SB(0, 1, 0);
    SA(1, 0, 1); SB(1, 1, 1);
    VM4;                                  // retire the 8 buf0 loads
    __builtin_amdgcn_s_barrier();
    __builtin_amdgcn_sched_barrier(0);

    for (int i = 0; i < 15; ++i) {
        const int t0 = 2 * i, t1 = t0 + 1;
        PHASE(0, 0, 0, SA(1, 1, t1);     SB(1, 0, t1);     , NOVM);  // P1
        PHASE(0, 0, 1,                                     , NOVM);  // P2
        PHASE(0, 1, 1, SA(0, 0, t0 + 2);                   , NOVM);  // P3
        PHASE(0, 1, 0, SB(0, 1, t0 + 2);                   , VM4);   // P4
        PHASE(1, 0, 0, SB(0, 0, t0 + 2); SA(0, 1, t0 + 2); , NOVM);  // P5
        PHASE(1, 0, 1,                                     , NOVM);  // P6
        PHASE(1, 1, 1, SA(1, 0, t1 + 2);                   , NOVM);  // P7
        PHASE(1, 1, 0, SB(1, 1, t1 + 2);                   , VM4);   // P8
    }
    // peeled last iteration (t0=30, t1=31): no forward stages, drain at P4
    PHASE(0, 0, 0, SA(1, 1, 31); SB(1, 0, 31); , NOVM);
    PHASE(0, 0, 1,                             , NOVM);
    PHASE(0, 1, 1,                             , NOVM);
    PHASE(0, 1, 0,                             , VM0);
    PHASE(1, 0, 0,                             , NOVM);
    PHASE(1, 0, 1,                             , NOVM);
    PHASE(1, 1, 1,                             , NOVM);
    PHASE(1, 1, 0,                             , NOVM);

    // fused sigmoid-gate epilogue
    #pragma unroll
    for (int ni = 0; ni < 2; ++ni) {
        const int col = n0 + wn * 32 + ni * 16 + l16;
        const float bgi = bg[col];
        const float bgf = bg[col + 1024];
        #pragma unroll
        for (int mh = 0; mh < 2; ++mh)
            #pragma unroll
            for (int mi = 0; mi < 4; ++mi) {
                const int row0 = m0 + mh * 128 + wm * 64 + mi * 16 + quad * 4;
                #pragma unroll
                for (int r = 0; r < 4; ++r) {
                    const size_t idx = (size_t)(row0 + r) * 1024 + col;
                    const float gi = 1.0f / (1.0f + __expf(-(acc[0][mh * 4 + mi][ni][r] + bgi)));
                    const float gf = 1.0f / (1.0f + __expf(-(acc[1][mh * 4 + mi][ni][r] + bgf)));
                    out[idx] = gi * iQ[idx] + gf * b2f(ffn[idx]);
                }
            }
    }
}

// ---------------------------------------------------------------------------
extern "C" void kernel_launch(void* const* d_in, const int* in_sizes, int n_in,
                              void* d_out, int out_size, void* d_ws, size_t ws_size,
                              hipStream_t stream) {
    const int B = 4, S = 2048, D = 1024, D2 = 2048;
    const int M = B * S;  // 8192

    const float* iQ = (const float*)d_in[0];
    const float* iV = (const float*)d_in[1];
    const float* W1 = (const float*)d_in[2];
    const float* b1 = (const float*)d_in[3];
    const float* W2 = (const float*)d_in[4];
    const float* b2 = (const float*)d_in[5];
    const float* Wg = (const float*)d_in[6];
    const float* bg = (const float*)d_in[7];
    float* out = (float*)d_out;

    // workspace, no aliasing (61 MB):
    u16*   regA = (u16*)d_ws;                    // avg -> ffn   (16 MB)
    u16*   regB = regA + (size_t)M * D;          // h            (16 MB)
    u16*   iQb  = regB + (size_t)M * D;          // iQ bf16      (16 MB)
    u16*   W1t  = iQb  + (size_t)M * D;          //              ( 2 MB)
    u16*   W2t  = W1t  + (size_t)D * D;          //              ( 2 MB)
    u16*   Wgt  = W2t  + (size_t)D * D;          //              ( 8 MB)
    float* csum = (float*)(Wgt + (size_t)D2 * D2); // B*64*D f32 ( 1 MB)

    u16* avg = regA;
    u16* ffn = regA;
    u16* h   = regB;

    // 1. all independent prologue work in one big dispatch (14592 blocks)
    prologue_kernel<<<14592, 256, 0, stream>>>(W1, W1t, W2, W2t, Wg, Wgt,
                                               iQ, iQb, iV, csum);
    // 2. causal cumulative mean
    scan_kernel<<<B * 64, 256, 0, stream>>>(iV, csum, avg);
    // 3. h = relu(avg @ W1 + b1)
    gemm_kernel<0><<<dim3(M / 128, D / 128), 256, 0, stream>>>(avg, W1t, b1, h, M, D, D);
    // 4. ffn = h @ W2 + b2   (overlays avg)
    gemm_kernel<1><<<dim3(M / 128, D / 128), 256, 0, stream>>>(h, W2t, b2, ffn, M, D, D);
    // 5. fused gate GEMM + sigmoid-gate epilogue (8-phase pipelined)
    gate8_kernel<<<256, 512, 0, stream>>>(iQb, ffn, Wgt, bg, iQ, out);
}

// Round 3
// 276.453 us; speedup vs baseline: 1.1033x; 1.0286x over previous
//
#include <hip/hip_runtime.h>
#include <hip/hip_bf16.h>
#include <cstdint>

typedef unsigned short u16;
typedef unsigned int   u32;

typedef __attribute__((ext_vector_type(8))) short short8;   // 8 x bf16 (4 VGPRs)
typedef __attribute__((ext_vector_type(4))) float f32x4;    // MFMA accumulator

__device__ __forceinline__ float b2f(u16 v) { return __uint_as_float(((u32)v) << 16); }
__device__ __forceinline__ u16 f2b(float f) {
    u32 u = __float_as_uint(f);
    u += 0x7FFFu + ((u >> 16) & 1u);   // round-to-nearest-even
    return (u16)(u >> 16);
}

#define G2L16(gp, lp) __builtin_amdgcn_global_load_lds(                       \
    (const __attribute__((address_space(1))) void*)(gp),                      \
    (__attribute__((address_space(3))) void*)(lp), 16, 0, 0)

// ---------------------------------------------------------------------------
// Fused prologue (unchanged): transposes, iQ cast, iV chunk sums.
// ---------------------------------------------------------------------------
__device__ __forceinline__ void transpose_body(const float* __restrict__ in,
                                               u16* __restrict__ out,
                                               int R, int C, int lb, int tilesX,
                                               float (*tile)[33]) {
    const int bx = (lb % tilesX) * 32;
    const int by = (lb / tilesX) * 32;
    const int tx = threadIdx.x & 31, ty = threadIdx.x >> 5;   // 32 x 8
    #pragma unroll
    for (int i = 0; i < 32; i += 8)
        tile[ty + i][tx] = in[(size_t)(by + ty + i) * C + (bx + tx)];
    __syncthreads();
    #pragma unroll
    for (int i = 0; i < 32; i += 8)
        out[(size_t)(bx + ty + i) * R + (by + tx)] = f2b(tile[tx][ty + i]);
}

__global__ void prologue_kernel(const float* __restrict__ W1, u16* __restrict__ W1t,
                                const float* __restrict__ W2, u16* __restrict__ W2t,
                                const float* __restrict__ Wg, u16* __restrict__ Wgt,
                                const float* __restrict__ iQ, u16* __restrict__ iQb,
                                const float* __restrict__ iV, float* __restrict__ csum) {
    __shared__ float tile[32][33];
    const int bid = blockIdx.x;
    const int tid = threadIdx.x;
    if (bid < 1024) {
        transpose_body(W1, W1t, 1024, 1024, bid, 32, tile);
    } else if (bid < 2048) {
        transpose_body(W2, W2t, 1024, 1024, bid - 1024, 32, tile);
    } else if (bid < 6144) {
        transpose_body(Wg, Wgt, 2048, 2048, bid - 2048, 64, tile);
    } else if (bid < 14336) {
        const size_t i = ((size_t)(bid - 6144) * 256 + tid) * 4;
        const float4 v = *(const float4*)(iQ + i);
        ushort4 o;
        o.x = f2b(v.x); o.y = f2b(v.y); o.z = f2b(v.z); o.w = f2b(v.w);
        *(ushort4*)(iQb + i) = o;
    } else {
        const int idx = bid - 14336;
        const int b = idx >> 6, c = idx & 63;
        const int d = tid * 4;
        const float* src = iV + ((size_t)(b * 2048 + c * 32)) * 1024 + d;
        float4 s = {0.f, 0.f, 0.f, 0.f};
        #pragma unroll 8
        for (int i = 0; i < 32; ++i) {
            const float4 v = *(const float4*)(src + (size_t)i * 1024);
            s.x += v.x; s.y += v.y; s.z += v.z; s.w += v.w;
        }
        *(float4*)(csum + ((size_t)(b * 64 + c)) * 1024 + d) = s;
    }
}

// ---------------------------------------------------------------------------
// Scan (unchanged): prefix over chunk sums + in-chunk serial scan -> avg bf16.
// ---------------------------------------------------------------------------
__global__ void scan_kernel(const float* __restrict__ iV, const float* __restrict__ csum,
                            u16* __restrict__ avg) {
    const int c = blockIdx.x & 63, b = blockIdx.x >> 6;
    const int d = threadIdx.x * 4;
    const float* cs = csum + (size_t)b * 64 * 1024 + d;
    float4 a0 = {0,0,0,0}, a1 = {0,0,0,0}, a2 = {0,0,0,0}, a3 = {0,0,0,0};
    int cc = 0;
    for (; cc + 4 <= c; cc += 4) {
        const float4 v0 = *(const float4*)(cs + (size_t)(cc + 0) * 1024);
        const float4 v1 = *(const float4*)(cs + (size_t)(cc + 1) * 1024);
        const float4 v2 = *(const float4*)(cs + (size_t)(cc + 2) * 1024);
        const float4 v3 = *(const float4*)(cs + (size_t)(cc + 3) * 1024);
        a0.x += v0.x; a0.y += v0.y; a0.z += v0.z; a0.w += v0.w;
        a1.x += v1.x; a1.y += v1.y; a1.z += v1.z; a1.w += v1.w;
        a2.x += v2.x; a2.y += v2.y; a2.z += v2.z; a2.w += v2.w;
        a3.x += v3.x; a3.y += v3.y; a3.z += v3.z; a3.w += v3.w;
    }
    for (; cc < c; ++cc) {
        const float4 v = *(const float4*)(cs + (size_t)cc * 1024);
        a0.x += v.x; a0.y += v.y; a0.z += v.z; a0.w += v.w;
    }
    float4 acc;
    acc.x = (a0.x + a1.x) + (a2.x + a3.x);
    acc.y = (a0.y + a1.y) + (a2.y + a3.y);
    acc.z = (a0.z + a1.z) + (a2.z + a3.z);
    acc.w = (a0.w + a1.w) + (a2.w + a3.w);

    const size_t off = ((size_t)(b * 2048 + c * 32)) * 1024 + d;
    const float* src = iV + off;
    u16*         dst = avg + off;
    const int s0 = c * 32;
    #pragma unroll 4
    for (int i = 0; i < 32; ++i) {
        const float4 v = *(const float4*)(src + (size_t)i * 1024);
        acc.x += v.x; acc.y += v.y; acc.z += v.z; acc.w += v.w;
        const float inv = 1.0f / (float)(s0 + i + 1);
        ushort4 o;
        o.x = f2b(acc.x * inv); o.y = f2b(acc.y * inv);
        o.z = f2b(acc.z * inv); o.w = f2b(acc.w * inv);
        *(ushort4*)(dst + (size_t)i * 1024) = o;
    }
}

// ---------------------------------------------------------------------------
// Round-0 proven MFMA GEMM (948 TF-class), BK=64, XOR-swizzled LDS.
// EPI: 0 = relu(x+b), 1 = x+b.
// ---------------------------------------------------------------------------
template <int EPI>
__global__ __launch_bounds__(256, 2)
void gemm_kernel(const u16* __restrict__ A, const u16* __restrict__ Bt,
                 const float* __restrict__ bias, u16* __restrict__ C,
                 int M, int N, int K) {
    __shared__ u16 As[128 * 64];
    __shared__ u16 Bs[128 * 64];

    const int tid  = threadIdx.x;
    const int m0   = blockIdx.x * 128;
    const int n0   = blockIdx.y * 128;
    const int wave = tid >> 6, lane = tid & 63;
    const int wm   = (wave & 1) << 6;
    const int wn   = (wave >> 1) << 6;
    const int quad = lane >> 4, l16 = lane & 15;

    f32x4 acc[4][4];
    #pragma unroll
    for (int i = 0; i < 4; ++i)
        #pragma unroll
        for (int j = 0; j < 4; ++j) acc[i][j] = (f32x4){0.f, 0.f, 0.f, 0.f};

    int oo[4], rr[4], qq[4];
    #pragma unroll
    for (int j = 0; j < 4; ++j) {
        oo[j] = tid * 16 + j * 4096;
        rr[j] = oo[j] >> 7;
        qq[j] = ((oo[j] >> 4) & 7) ^ (rr[j] & 7);
    }

    const int ktiles = K >> 6;
    for (int kt = 0; kt < ktiles; ++kt) {
        const int kb = kt << 6;
        #pragma unroll
        for (int j = 0; j < 4; ++j) {
            G2L16((const char*)A  + ((size_t)(m0 + rr[j]) * K + kb) * 2 + qq[j] * 16,
                  (char*)As + oo[j]);
            G2L16((const char*)Bt + ((size_t)(n0 + rr[j]) * K + kb) * 2 + qq[j] * 16,
                  (char*)Bs + oo[j]);
        }
        __syncthreads();

        #pragma unroll
        for (int h = 0; h < 2; ++h) {
            short8 af[4], bf[4];
            #pragma unroll
            for (int mi = 0; mi < 4; ++mi) {
                const int R = wm + mi * 16 + l16;
                af[mi] = *(const short8*)(As + R * 64 + ((((h << 2) | quad) ^ (R & 7)) << 3));
            }
            #pragma unroll
            for (int ni = 0; ni < 4; ++ni) {
                const int R = wn + ni * 16 + l16;
                bf[ni] = *(const short8*)(Bs + R * 64 + ((((h << 2) | quad) ^ (R & 7)) << 3));
            }
            #pragma unroll
            for (int mi = 0; mi < 4; ++mi)
                #pragma unroll
                for (int ni = 0; ni < 4; ++ni)
                    acc[mi][ni] = __builtin_amdgcn_mfma_f32_16x16x32_bf16(
                        af[mi], bf[ni], acc[mi][ni], 0, 0, 0);
        }
        __syncthreads();
    }

    #pragma unroll
    for (int ni = 0; ni < 4; ++ni) {
        const int col = n0 + wn + ni * 16 + l16;
        const float bv = bias[col];
        #pragma unroll
        for (int mi = 0; mi < 4; ++mi) {
            const int row0 = m0 + wm + mi * 16 + quad * 4;
            #pragma unroll
            for (int r = 0; r < 4; ++r) {
                float v = acc[mi][ni][r] + bv;
                if (EPI == 0) v = fmaxf(v, 0.f);
                C[(size_t)(row0 + r) * N + col] = f2b(v);
            }
        }
    }
}

// ---------------------------------------------------------------------------
// 4-phase gate GEMM: merged quadrants, B-frags register-resident per K-tile.
// Per K-tile per wave: 24 ds_read_b128 (was 48) feeding 64 MFMA.
// Phase = {8 A-frag reads [+8 B-frag reads in MH0 phases], 2 half-tile stages,
//          barrier, lgkmcnt(0), setprio(1), 32 MFMA, setprio(0), vmcnt?, barrier}
// Counted vmcnt(4) only at P2/P4 (retires loads >=2 phases old); tail peeled.
// Stage rotation (slot-death verified):
//   P1(b0,MH0+B): SA(1,A1,t1) SB(1,B1,t1)       [dead: prev P4/P3]
//   P2(b0,MH1)  : SA(0,A0,t0+2) SB(0,B0,t0+2)   [dead: P1]          VM4
//   P3(b1,MH0+B): SB(0,B1,t0+2) SA(0,A1,t0+2)   [dead: P1/P2]
//   P4(b1,MH1)  : SA(1,A0,t1+2) SB(1,B0,t1+2)   [dead: P3]          VM4
// ---------------------------------------------------------------------------
#define VM4  asm volatile("s_waitcnt vmcnt(4)" ::: "memory")
#define VM0  asm volatile("s_waitcnt vmcnt(0)" ::: "memory")
#define NOVM ((void)0)

#define SA(BUF, MH, T) do {                                                     \
    const char* b_ = ((T) < 16) ? ((const char*)iQb + (size_t)(T) * 128)        \
                                : ((const char*)ffn + (size_t)((T) - 16) * 128); \
    G2L16(b_ + gA[MH][0], (char*)&As[BUF][MH][0] + lo[0]);                      \
    G2L16(b_ + gA[MH][1], (char*)&As[BUF][MH][0] + lo[1]);                      \
  } while (0)

#define SB(BUF, GG, T) do {                                                     \
    const char* b_ = (const char*)Wgt + (size_t)(T) * 128;                      \
    G2L16(b_ + gB[GG][0], (char*)&Bs[BUF][GG][0] + lo[0]);                      \
    G2L16(b_ + gB[GG][1], (char*)&Bs[BUF][GG][0] + lo[1]);                      \
  } while (0)

// RDB: 1 = also read B fragments (MH0 phases), 0 = reuse bf registers.
#define PHASE(BUF, MH, RDB, STAGES, VMW) do {                                   \
    short8 af[4][2];                                                            \
    {                                                                           \
      const char* Ab_ = (const char*)&As[BUF][MH][0];                           \
      _Pragma("unroll")                                                         \
      for (int mi = 0; mi < 4; ++mi) {                                          \
        af[mi][0] = *(const short8*)(Ab_ + aF[mi][0]);                          \
        af[mi][1] = *(const short8*)(Ab_ + aF[mi][1]);                          \
      }                                                                         \
      if (RDB) {                                                                \
        const char* B0_ = (const char*)&Bs[BUF][0][0];                          \
        const char* B1_ = (const char*)&Bs[BUF][1][0];                          \
        _Pragma("unroll")                                                       \
        for (int ni = 0; ni < 2; ++ni) {                                        \
          _Pragma("unroll")                                                     \
          for (int ks = 0; ks < 2; ++ks) {                                      \
            bf[0][ni][ks] = *(const short8*)(B0_ + bF[ni][ks]);                 \
            bf[1][ni][ks] = *(const short8*)(B1_ + bF[ni][ks]);                 \
          }                                                                     \
        }                                                                       \
      }                                                                         \
    }                                                                           \
    STAGES                                                                      \
    __builtin_amdgcn_sched_barrier(0);                                          \
    __builtin_amdgcn_s_barrier();                                               \
    asm volatile("s_waitcnt lgkmcnt(0)" ::: "memory");                          \
    __builtin_amdgcn_sched_barrier(0);                                          \
    __builtin_amdgcn_s_setprio(1);                                              \
    _Pragma("unroll")                                                           \
    for (int ks = 0; ks < 2; ++ks) {                                            \
      _Pragma("unroll")                                                         \
      for (int mi = 0; mi < 4; ++mi) {                                          \
        _Pragma("unroll")                                                       \
        for (int ni = 0; ni < 2; ++ni) {                                        \
          acc[0][(MH) * 4 + mi][ni] = __builtin_amdgcn_mfma_f32_16x16x32_bf16(  \
              af[mi][ks], bf[0][ni][ks], acc[0][(MH) * 4 + mi][ni], 0, 0, 0);   \
          acc[1][(MH) * 4 + mi][ni] = __builtin_amdgcn_mfma_f32_16x16x32_bf16(  \
              af[mi][ks], bf[1][ni][ks], acc[1][(MH) * 4 + mi][ni], 0, 0, 0);   \
        }                                                                       \
      }                                                                         \
    }                                                                           \
    __builtin_amdgcn_s_setprio(0);                                              \
    __builtin_amdgcn_sched_barrier(0);                                          \
    VMW;                                                                        \
    __builtin_amdgcn_s_barrier();                                               \
    __builtin_amdgcn_sched_barrier(0);                                          \
  } while (0)

__global__ __launch_bounds__(512, 2)
void gate4_kernel(const u16* __restrict__ iQb, const u16* __restrict__ ffn,
                  const u16* __restrict__ Wgt, const float* __restrict__ bg,
                  const float* __restrict__ iQ, float* __restrict__ out) {
    __shared__ u16 As[2][2][128 * 64];   // [buf][mh] 16KB half-tiles
    __shared__ u16 Bs[2][2][128 * 64];   // [buf][g]

    const int tid  = threadIdx.x;
    const int bid  = blockIdx.x;
    const int m0   = (bid & 31) * 256;   // m fast-varying: xcd = m_tile % 8
    const int n0   = (bid >> 5) * 128;
    const int wave = tid >> 6, lane = tid & 63;
    const int wm   = wave & 1;
    const int wn   = wave >> 1;
    const int quad = lane >> 4, l16 = lane & 15;

    // staging constants: 2 x global_load_lds(16B) per half-tile per thread
    u32 lo[2], gA[2][2], gB[2][2];
    #pragma unroll
    for (int j = 0; j < 2; ++j) {
        const u32 o = (u32)tid * 16 + (u32)j * 8192;
        const u32 r = o >> 7;
        const u32 q = ((o >> 4) & 7) ^ (r & 7);
        lo[j]    = o;
        gA[0][j] = (u32)(m0 + r) * 2048 + q * 16;          // A row = 2048 B
        gA[1][j] = (u32)(m0 + 128 + r) * 2048 + q * 16;
        gB[0][j] = (u32)(n0 + r) * 4096 + q * 16;          // Wgt row = 4096 B
        gB[1][j] = (u32)(n0 + 1024 + r) * 4096 + q * 16;
    }

    // fragment ds_read byte offsets (swizzle slot = (ks*4+quad)^(R&7))
    u32 aF[4][2], bF[2][2];
    #pragma unroll
    for (int mi = 0; mi < 4; ++mi) {
        const int R = wm * 64 + mi * 16 + l16;
        #pragma unroll
        for (int ks = 0; ks < 2; ++ks)
            aF[mi][ks] = (u32)R * 128 + (u32)((((ks << 2) | quad) ^ (R & 7)) << 4);
    }
    #pragma unroll
    for (int ni = 0; ni < 2; ++ni) {
        const int R = wn * 32 + ni * 16 + l16;
        #pragma unroll
        for (int ks = 0; ks < 2; ++ks)
            bF[ni][ks] = (u32)R * 128 + (u32)((((ks << 2) | quad) ^ (R & 7)) << 4);
    }

    f32x4 acc[2][8][2];
    #pragma unroll
    for (int g = 0; g < 2; ++g)
        #pragma unroll
        for (int mf = 0; mf < 8; ++mf)
            #pragma unroll
            for (int ni = 0; ni < 2; ++ni)
                acc[g][mf][ni] = (f32x4){0.f, 0.f, 0.f, 0.f};

    short8 bf[2][2][2];   // [g][ni][ks], persistent across MH0->MH1 phase pairs

    // prologue: buf0 <- tile0 full (8 loads); buf1 <- tile1 A0,B0 (4 loads)
    SA(0, 0, 0); SA(0, 1, 0); SB(0, 0, 0); SB(0, 1, 0);
    SA(1, 0, 1); SB(1, 0, 1);
    VM4;                                  // retire the 8 buf0 loads
    __builtin_amdgcn_s_barrier();
    __builtin_amdgcn_sched_barrier(0);

    for (int i = 0; i < 15; ++i) {
        const int t0 = 2 * i, t1 = t0 + 1;
        PHASE(0, 0, 1, SA(1, 1, t1);     SB(1, 1, t1);     , NOVM);  // P1
        PHASE(0, 1, 0, SA(0, 0, t0 + 2); SB(0, 0, t0 + 2); , VM4);   // P2
        PHASE(1, 0, 1, SB(0, 1, t0 + 2); SA(0, 1, t0 + 2); , NOVM);  // P3
        PHASE(1, 1, 0, SA(1, 0, t1 + 2); SB(1, 0, t1 + 2); , VM4);   // P4
    }
    // peeled last iteration (t0=30, t1=31): only t1's remaining halves staged
    PHASE(0, 0, 1, SA(1, 1, 31); SB(1, 1, 31); , NOVM);
    PHASE(0, 1, 0,                             , VM0);
    PHASE(1, 0, 1,                             , NOVM);
    PHASE(1, 1, 0,                             , NOVM);

    // fused sigmoid-gate epilogue
    #pragma unroll
    for (int ni = 0; ni < 2; ++ni) {
        const int col = n0 + wn * 32 + ni * 16 + l16;
        const float bgi = bg[col];
        const float bgf = bg[col + 1024];
        #pragma unroll
        for (int mh = 0; mh < 2; ++mh)
            #pragma unroll
            for (int mi = 0; mi < 4; ++mi) {
                const int row0 = m0 + mh * 128 + wm * 64 + mi * 16 + quad * 4;
                #pragma unroll
                for (int r = 0; r < 4; ++r) {
                    const size_t idx = (size_t)(row0 + r) * 1024 + col;
                    const float gi = 1.0f / (1.0f + __expf(-(acc[0][mh * 4 + mi][ni][r] + bgi)));
                    const float gf = 1.0f / (1.0f + __expf(-(acc[1][mh * 4 + mi][ni][r] + bgf)));
                    out[idx] = gi * iQ[idx] + gf * b2f(ffn[idx]);
                }
            }
    }
}

// ---------------------------------------------------------------------------
extern "C" void kernel_launch(void* const* d_in, const int* in_sizes, int n_in,
                              void* d_out, int out_size, void* d_ws, size_t ws_size,
                              hipStream_t stream) {
    const int B = 4, S = 2048, D = 1024, D2 = 2048;
    const int M = B * S;  // 8192

    const float* iQ = (const float*)d_in[0];
    const float* iV = (const float*)d_in[1];
    const float* W1 = (const float*)d_in[2];
    const float* b1 = (const float*)d_in[3];
    const float* W2 = (const float*)d_in[4];
    const float* b2 = (const float*)d_in[5];
    const float* Wg = (const float*)d_in[6];
    const float* bg = (const float*)d_in[7];
    float* out = (float*)d_out;

    // workspace, no aliasing (61 MB):
    u16*   regA = (u16*)d_ws;                    // avg -> ffn   (16 MB)
    u16*   regB = regA + (size_t)M * D;          // h            (16 MB)
    u16*   iQb  = regB + (size_t)M * D;          // iQ bf16      (16 MB)
    u16*   W1t  = iQb  + (size_t)M * D;          //              ( 2 MB)
    u16*   W2t  = W1t  + (size_t)D * D;          //              ( 2 MB)
    u16*   Wgt  = W2t  + (size_t)D * D;          //              ( 8 MB)
    float* csum = (float*)(Wgt + (size_t)D2 * D2); // B*64*D f32 ( 1 MB)

    u16* avg = regA;
    u16* ffn = regA;
    u16* h   = regB;

    // 1. all independent prologue work in one big dispatch (14592 blocks)
    prologue_kernel<<<14592, 256, 0, stream>>>(W1, W1t, W2, W2t, Wg, Wgt,
                                               iQ, iQb, iV, csum);
    // 2. causal cumulative mean
    scan_kernel<<<B * 64, 256, 0, stream>>>(iV, csum, avg);
    // 3. h = relu(avg @ W1 + b1)
    gemm_kernel<0><<<dim3(M / 128, D / 128), 256, 0, stream>>>(avg, W1t, b1, h, M, D, D);
    // 4. ffn = h @ W2 + b2   (overlays avg)
    gemm_kernel<1><<<dim3(M / 128, D / 128), 256, 0, stream>>>(h, W2t, b2, ffn, M, D, D);
    // 5. fused gate GEMM + sigmoid-gate epilogue (4-phase pipelined)
    gate4_kernel<<<256, 512, 0, stream>>>(iQb, ffn, Wgt, bg, iQ, out);
}

// Round 4
// 274.906 us; speedup vs baseline: 1.1095x; 1.0056x over previous
//
#include <hip/hip_runtime.h>
#include <hip/hip_bf16.h>
#include <cstdint>

typedef unsigned short u16;
typedef unsigned int   u32;

typedef __attribute__((ext_vector_type(8))) short short8;   // 8 x bf16 (4 VGPRs)
typedef __attribute__((ext_vector_type(4))) float f32x4;    // MFMA accumulator

__device__ __forceinline__ float b2f(u16 v) { return __uint_as_float(((u32)v) << 16); }
__device__ __forceinline__ u16 f2b(float f) {
    u32 u = __float_as_uint(f);
    u += 0x7FFFu + ((u >> 16) & 1u);   // round-to-nearest-even
    return (u16)(u >> 16);
}

#define G2L16(gp, lp) __builtin_amdgcn_global_load_lds(                       \
    (const __attribute__((address_space(1))) void*)(gp),                      \
    (__attribute__((address_space(3))) void*)(lp), 16, 0, 0)

// ---------------------------------------------------------------------------
// Fused prologue (unchanged): transposes, iQ cast, iV chunk sums.
// ---------------------------------------------------------------------------
__device__ __forceinline__ void transpose_body(const float* __restrict__ in,
                                               u16* __restrict__ out,
                                               int R, int C, int lb, int tilesX,
                                               float (*tile)[33]) {
    const int bx = (lb % tilesX) * 32;
    const int by = (lb / tilesX) * 32;
    const int tx = threadIdx.x & 31, ty = threadIdx.x >> 5;   // 32 x 8
    #pragma unroll
    for (int i = 0; i < 32; i += 8)
        tile[ty + i][tx] = in[(size_t)(by + ty + i) * C + (bx + tx)];
    __syncthreads();
    #pragma unroll
    for (int i = 0; i < 32; i += 8)
        out[(size_t)(bx + ty + i) * R + (by + tx)] = f2b(tile[tx][ty + i]);
}

__global__ void prologue_kernel(const float* __restrict__ W1, u16* __restrict__ W1t,
                                const float* __restrict__ W2, u16* __restrict__ W2t,
                                const float* __restrict__ Wg, u16* __restrict__ Wgt,
                                const float* __restrict__ iQ, u16* __restrict__ iQb,
                                const float* __restrict__ iV, float* __restrict__ csum) {
    __shared__ float tile[32][33];
    const int bid = blockIdx.x;
    const int tid = threadIdx.x;
    if (bid < 1024) {
        transpose_body(W1, W1t, 1024, 1024, bid, 32, tile);
    } else if (bid < 2048) {
        transpose_body(W2, W2t, 1024, 1024, bid - 1024, 32, tile);
    } else if (bid < 6144) {
        transpose_body(Wg, Wgt, 2048, 2048, bid - 2048, 64, tile);
    } else if (bid < 14336) {
        const size_t i = ((size_t)(bid - 6144) * 256 + tid) * 4;
        const float4 v = *(const float4*)(iQ + i);
        ushort4 o;
        o.x = f2b(v.x); o.y = f2b(v.y); o.z = f2b(v.z); o.w = f2b(v.w);
        *(ushort4*)(iQb + i) = o;
    } else {
        const int idx = bid - 14336;
        const int b = idx >> 6, c = idx & 63;
        const int d = tid * 4;
        const float* src = iV + ((size_t)(b * 2048 + c * 32)) * 1024 + d;
        float4 s = {0.f, 0.f, 0.f, 0.f};
        #pragma unroll 8
        for (int i = 0; i < 32; ++i) {
            const float4 v = *(const float4*)(src + (size_t)i * 1024);
            s.x += v.x; s.y += v.y; s.z += v.z; s.w += v.w;
        }
        *(float4*)(csum + ((size_t)(b * 64 + c)) * 1024 + d) = s;
    }
}

// ---------------------------------------------------------------------------
// Scan (unchanged): prefix over chunk sums + in-chunk serial scan -> avg bf16.
// ---------------------------------------------------------------------------
__global__ void scan_kernel(const float* __restrict__ iV, const float* __restrict__ csum,
                            u16* __restrict__ avg) {
    const int c = blockIdx.x & 63, b = blockIdx.x >> 6;
    const int d = threadIdx.x * 4;
    const float* cs = csum + (size_t)b * 64 * 1024 + d;
    float4 a0 = {0,0,0,0}, a1 = {0,0,0,0}, a2 = {0,0,0,0}, a3 = {0,0,0,0};
    int cc = 0;
    for (; cc + 4 <= c; cc += 4) {
        const float4 v0 = *(const float4*)(cs + (size_t)(cc + 0) * 1024);
        const float4 v1 = *(const float4*)(cs + (size_t)(cc + 1) * 1024);
        const float4 v2 = *(const float4*)(cs + (size_t)(cc + 2) * 1024);
        const float4 v3 = *(const float4*)(cs + (size_t)(cc + 3) * 1024);
        a0.x += v0.x; a0.y += v0.y; a0.z += v0.z; a0.w += v0.w;
        a1.x += v1.x; a1.y += v1.y; a1.z += v1.z; a1.w += v1.w;
        a2.x += v2.x; a2.y += v2.y; a2.z += v2.z; a2.w += v2.w;
        a3.x += v3.x; a3.y += v3.y; a3.z += v3.z; a3.w += v3.w;
    }
    for (; cc < c; ++cc) {
        const float4 v = *(const float4*)(cs + (size_t)cc * 1024);
        a0.x += v.x; a0.y += v.y; a0.z += v.z; a0.w += v.w;
    }
    float4 acc;
    acc.x = (a0.x + a1.x) + (a2.x + a3.x);
    acc.y = (a0.y + a1.y) + (a2.y + a3.y);
    acc.z = (a0.z + a1.z) + (a2.z + a3.z);
    acc.w = (a0.w + a1.w) + (a2.w + a3.w);

    const size_t off = ((size_t)(b * 2048 + c * 32)) * 1024 + d;
    const float* src = iV + off;
    u16*         dst = avg + off;
    const int s0 = c * 32;
    #pragma unroll 4
    for (int i = 0; i < 32; ++i) {
        const float4 v = *(const float4*)(src + (size_t)i * 1024);
        acc.x += v.x; acc.y += v.y; acc.z += v.z; acc.w += v.w;
        const float inv = 1.0f / (float)(s0 + i + 1);
        ushort4 o;
        o.x = f2b(acc.x * inv); o.y = f2b(acc.y * inv);
        o.z = f2b(acc.z * inv); o.w = f2b(acc.w * inv);
        *(ushort4*)(dst + (size_t)i * 1024) = o;
    }
}

// ---------------------------------------------------------------------------
// Round-0 proven MFMA GEMM (948 TF-class), BK=64, XOR-swizzled LDS.
// EPI: 0 = relu(x+b), 1 = x+b.
// ---------------------------------------------------------------------------
template <int EPI>
__global__ __launch_bounds__(256, 2)
void gemm_kernel(const u16* __restrict__ A, const u16* __restrict__ Bt,
                 const float* __restrict__ bias, u16* __restrict__ C,
                 int M, int N, int K) {
    __shared__ u16 As[128 * 64];
    __shared__ u16 Bs[128 * 64];

    const int tid  = threadIdx.x;
    const int m0   = blockIdx.x * 128;
    const int n0   = blockIdx.y * 128;
    const int wave = tid >> 6, lane = tid & 63;
    const int wm   = (wave & 1) << 6;
    const int wn   = (wave >> 1) << 6;
    const int quad = lane >> 4, l16 = lane & 15;

    f32x4 acc[4][4];
    #pragma unroll
    for (int i = 0; i < 4; ++i)
        #pragma unroll
        for (int j = 0; j < 4; ++j) acc[i][j] = (f32x4){0.f, 0.f, 0.f, 0.f};

    int oo[4], rr[4], qq[4];
    #pragma unroll
    for (int j = 0; j < 4; ++j) {
        oo[j] = tid * 16 + j * 4096;
        rr[j] = oo[j] >> 7;
        qq[j] = ((oo[j] >> 4) & 7) ^ (rr[j] & 7);
    }

    const int ktiles = K >> 6;
    for (int kt = 0; kt < ktiles; ++kt) {
        const int kb = kt << 6;
        #pragma unroll
        for (int j = 0; j < 4; ++j) {
            G2L16((const char*)A  + ((size_t)(m0 + rr[j]) * K + kb) * 2 + qq[j] * 16,
                  (char*)As + oo[j]);
            G2L16((const char*)Bt + ((size_t)(n0 + rr[j]) * K + kb) * 2 + qq[j] * 16,
                  (char*)Bs + oo[j]);
        }
        __syncthreads();

        #pragma unroll
        for (int h = 0; h < 2; ++h) {
            short8 af[4], bf[4];
            #pragma unroll
            for (int mi = 0; mi < 4; ++mi) {
                const int R = wm + mi * 16 + l16;
                af[mi] = *(const short8*)(As + R * 64 + ((((h << 2) | quad) ^ (R & 7)) << 3));
            }
            #pragma unroll
            for (int ni = 0; ni < 4; ++ni) {
                const int R = wn + ni * 16 + l16;
                bf[ni] = *(const short8*)(Bs + R * 64 + ((((h << 2) | quad) ^ (R & 7)) << 3));
            }
            #pragma unroll
            for (int mi = 0; mi < 4; ++mi)
                #pragma unroll
                for (int ni = 0; ni < 4; ++ni)
                    acc[mi][ni] = __builtin_amdgcn_mfma_f32_16x16x32_bf16(
                        af[mi], bf[ni], acc[mi][ni], 0, 0, 0);
        }
        __syncthreads();
    }

    #pragma unroll
    for (int ni = 0; ni < 4; ++ni) {
        const int col = n0 + wn + ni * 16 + l16;
        const float bv = bias[col];
        #pragma unroll
        for (int mi = 0; mi < 4; ++mi) {
            const int row0 = m0 + wm + mi * 16 + quad * 4;
            #pragma unroll
            for (int r = 0; r < 4; ++r) {
                float v = acc[mi][ni][r] + bv;
                if (EPI == 0) v = fmaxf(v, 0.f);
                C[(size_t)(row0 + r) * N + col] = f2b(v);
            }
        }
    }
}

// ---------------------------------------------------------------------------
// 8-phase gate GEMM, m201-faithful: 16 MFMA + 4-8 ds_reads + <=1 half-tile
// stage per phase, vmcnt(6) only at P4/P8. No duplicate reads: per K-tile
// 24 ds_read_b128 / 64 MFMA per wave. Phases = (MH, ks) sub-tiles; B-frags
// for ks read once in the MH0 phase, register-resident through MH1 phase.
// Stage rotation (slot-death verified, deadlines vs vmcnt(6)@P4/P8):
//   P1: b1.A1(t1)      P3: b0.A0,b0.B0(t0+2)  P4: b0.B1(t0+2)  [VM6]
//   P5: b0.A1(t0+2)    P7: b1.A0,b1.B0(t1+2)  P8: b1.B1(t1+2)  [VM6]
// Last iteration peeled: only P1 stages; VM0 at P4.
// ---------------------------------------------------------------------------
#define VM6  asm volatile("s_waitcnt vmcnt(6)" ::: "memory")
#define VM0  asm volatile("s_waitcnt vmcnt(0)" ::: "memory")
#define NOVM ((void)0)

#define SA(BUF, MH, T) do {                                                     \
    const char* b_ = ((T) < 16) ? ((const char*)iQb + (size_t)(T) * 128)        \
                                : ((const char*)ffn + (size_t)((T) - 16) * 128); \
    G2L16(b_ + gA[MH][0], (char*)&As[BUF][MH][0] + lo[0]);                      \
    G2L16(b_ + gA[MH][1], (char*)&As[BUF][MH][0] + lo[1]);                      \
  } while (0)

#define SB(BUF, GG, T) do {                                                     \
    const char* b_ = (const char*)Wgt + (size_t)(T) * 128;                      \
    G2L16(b_ + gB[GG][0], (char*)&Bs[BUF][GG][0] + lo[0]);                      \
    G2L16(b_ + gB[GG][1], (char*)&Bs[BUF][GG][0] + lo[1]);                      \
  } while (0)

// One phase: 4 A-frag reads [+4 B-frag reads if RDB], <=1 stage, barrier,
// lgkmcnt(0), setprio(1), 16 MFMA (mi x ni x g at this ks), setprio(0), vmcnt?,
// barrier. KS/MH/BUF/RDB are literals -> all register indices compile-time.
#define PHASE(BUF, MH, KS, RDB, STAGES, VMW) do {                               \
    short8 af[4];                                                               \
    {                                                                           \
      const char* Ab_ = (const char*)&As[BUF][MH][0];                           \
      _Pragma("unroll")                                                         \
      for (int mi = 0; mi < 4; ++mi)                                            \
        af[mi] = *(const short8*)(Ab_ + aF[mi][KS]);                            \
      if (RDB) {                                                                \
        const char* B0_ = (const char*)&Bs[BUF][0][0];                          \
        const char* B1_ = (const char*)&Bs[BUF][1][0];                          \
        _Pragma("unroll")                                                       \
        for (int ni = 0; ni < 2; ++ni) {                                        \
          bf[0][ni][KS] = *(const short8*)(B0_ + bF[ni][KS]);                   \
          bf[1][ni][KS] = *(const short8*)(B1_ + bF[ni][KS]);                   \
        }                                                                       \
      }                                                                         \
    }                                                                           \
    STAGES                                                                      \
    __builtin_amdgcn_sched_barrier(0);                                          \
    __builtin_amdgcn_s_barrier();                                               \
    asm volatile("s_waitcnt lgkmcnt(0)" ::: "memory");                          \
    __builtin_amdgcn_sched_barrier(0);                                          \
    __builtin_amdgcn_s_setprio(1);                                              \
    _Pragma("unroll")                                                           \
    for (int mi = 0; mi < 4; ++mi) {                                            \
      _Pragma("unroll")                                                         \
      for (int ni = 0; ni < 2; ++ni) {                                          \
        acc[0][(MH) * 4 + mi][ni] = __builtin_amdgcn_mfma_f32_16x16x32_bf16(    \
            af[mi], bf[0][ni][KS], acc[0][(MH) * 4 + mi][ni], 0, 0, 0);         \
        acc[1][(MH) * 4 + mi][ni] = __builtin_amdgcn_mfma_f32_16x16x32_bf16(    \
            af[mi], bf[1][ni][KS], acc[1][(MH) * 4 + mi][ni], 0, 0, 0);         \
      }                                                                         \
    }                                                                           \
    __builtin_amdgcn_s_setprio(0);                                              \
    __builtin_amdgcn_sched_barrier(0);                                          \
    VMW;                                                                        \
    __builtin_amdgcn_s_barrier();                                               \
    __builtin_amdgcn_sched_barrier(0);                                          \
  } while (0)

__global__ __launch_bounds__(512, 2)
void gate8f_kernel(const u16* __restrict__ iQb, const u16* __restrict__ ffn,
                   const u16* __restrict__ Wgt, const float* __restrict__ bg,
                   const float* __restrict__ iQ, float* __restrict__ out) {
    __shared__ u16 As[2][2][128 * 64];   // [buf][mh] 16KB half-tiles
    __shared__ u16 Bs[2][2][128 * 64];   // [buf][g]

    const int tid  = threadIdx.x;
    const int bid  = blockIdx.x;
    const int m0   = (bid & 31) * 256;   // m fast-varying: xcd = m_tile % 8
    const int n0   = (bid >> 5) * 128;
    const int wave = tid >> 6, lane = tid & 63;
    const int wm   = wave & 1;
    const int wn   = wave >> 1;
    const int quad = lane >> 4, l16 = lane & 15;

    // staging constants: 2 x global_load_lds(16B) per half-tile per thread
    u32 lo[2], gA[2][2], gB[2][2];
    #pragma unroll
    for (int j = 0; j < 2; ++j) {
        const u32 o = (u32)tid * 16 + (u32)j * 8192;
        const u32 r = o >> 7;
        const u32 q = ((o >> 4) & 7) ^ (r & 7);
        lo[j]    = o;
        gA[0][j] = (u32)(m0 + r) * 2048 + q * 16;          // A row = 2048 B
        gA[1][j] = (u32)(m0 + 128 + r) * 2048 + q * 16;
        gB[0][j] = (u32)(n0 + r) * 4096 + q * 16;          // Wgt row = 4096 B
        gB[1][j] = (u32)(n0 + 1024 + r) * 4096 + q * 16;
    }

    // fragment ds_read byte offsets (swizzle slot = (ks*4+quad)^(R&7))
    u32 aF[4][2], bF[2][2];
    #pragma unroll
    for (int mi = 0; mi < 4; ++mi) {
        const int R = wm * 64 + mi * 16 + l16;
        #pragma unroll
        for (int ks = 0; ks < 2; ++ks)
            aF[mi][ks] = (u32)R * 128 + (u32)((((ks << 2) | quad) ^ (R & 7)) << 4);
    }
    #pragma unroll
    for (int ni = 0; ni < 2; ++ni) {
        const int R = wn * 32 + ni * 16 + l16;
        #pragma unroll
        for (int ks = 0; ks < 2; ++ks)
            bF[ni][ks] = (u32)R * 128 + (u32)((((ks << 2) | quad) ^ (R & 7)) << 4);
    }

    f32x4 acc[2][8][2];
    #pragma unroll
    for (int g = 0; g < 2; ++g)
        #pragma unroll
        for (int mf = 0; mf < 8; ++mf)
            #pragma unroll
            for (int ni = 0; ni < 2; ++ni)
                acc[g][mf][ni] = (f32x4){0.f, 0.f, 0.f, 0.f};

    short8 bf[2][2][2];   // [g][ni][ks]; ks-slice read in MH0 phase, reused in MH1

    // prologue: b0 <- tile0 full (8 loads); b1 <- tile1 {A0,B0,B1} (6 loads)
    SA(0, 0, 0); SA(0, 1, 0); SB(0, 0, 0); SB(0, 1, 0);
    SA(1, 0, 1); SB(1, 0, 1); SB(1, 1, 1);
    VM6;                                  // retire the 8 b0 loads
    __builtin_amdgcn_s_barrier();
    __builtin_amdgcn_sched_barrier(0);

    for (int i = 0; i < 15; ++i) {
        const int t0 = 2 * i, t1 = t0 + 1;
        PHASE(0, 0, 0, 1, SA(1, 1, t1);                    , NOVM);  // P1
        PHASE(0, 0, 1, 1,                                  , NOVM);  // P2
        PHASE(0, 1, 0, 0, SA(0, 0, t0 + 2); SB(0, 0, t0 + 2); , NOVM);  // P3
        PHASE(0, 1, 1, 0, SB(0, 1, t0 + 2);                , VM6);   // P4
        PHASE(1, 0, 0, 1, SA(0, 1, t0 + 2);                , NOVM);  // P5
        PHASE(1, 0, 1, 1,                                  , NOVM);  // P6
        PHASE(1, 1, 0, 0, SA(1, 0, t1 + 2); SB(1, 0, t1 + 2); , NOVM);  // P7
        PHASE(1, 1, 1, 0, SB(1, 1, t1 + 2);                , VM6);   // P8
    }
    // peeled last iteration (t0=30, t1=31): only b1.A1(31) staged; drain at P4
    PHASE(0, 0, 0, 1, SA(1, 1, 31);                        , NOVM);
    PHASE(0, 0, 1, 1,                                      , NOVM);
    PHASE(0, 1, 0, 0,                                      , NOVM);
    PHASE(0, 1, 1, 0,                                      , VM0);
    PHASE(1, 0, 0, 1,                                      , NOVM);
    PHASE(1, 0, 1, 1,                                      , NOVM);
    PHASE(1, 1, 0, 0,                                      , NOVM);
    PHASE(1, 1, 1, 0,                                      , NOVM);

    // fused sigmoid-gate epilogue
    #pragma unroll
    for (int ni = 0; ni < 2; ++ni) {
        const int col = n0 + wn * 32 + ni * 16 + l16;
        const float bgi = bg[col];
        const float bgf = bg[col + 1024];
        #pragma unroll
        for (int mh = 0; mh < 2; ++mh)
            #pragma unroll
            for (int mi = 0; mi < 4; ++mi) {
                const int row0 = m0 + mh * 128 + wm * 64 + mi * 16 + quad * 4;
                #pragma unroll
                for (int r = 0; r < 4; ++r) {
                    const size_t idx = (size_t)(row0 + r) * 1024 + col;
                    const float gi = 1.0f / (1.0f + __expf(-(acc[0][mh * 4 + mi][ni][r] + bgi)));
                    const float gf = 1.0f / (1.0f + __expf(-(acc[1][mh * 4 + mi][ni][r] + bgf)));
                    out[idx] = gi * iQ[idx] + gf * b2f(ffn[idx]);
                }
            }
    }
}

// ---------------------------------------------------------------------------
extern "C" void kernel_launch(void* const* d_in, const int* in_sizes, int n_in,
                              void* d_out, int out_size, void* d_ws, size_t ws_size,
                              hipStream_t stream) {
    const int B = 4, S = 2048, D = 1024, D2 = 2048;
    const int M = B * S;  // 8192

    const float* iQ = (const float*)d_in[0];
    const float* iV = (const float*)d_in[1];
    const float* W1 = (const float*)d_in[2];
    const float* b1 = (const float*)d_in[3];
    const float* W2 = (const float*)d_in[4];
    const float* b2 = (const float*)d_in[5];
    const float* Wg = (const float*)d_in[6];
    const float* bg = (const float*)d_in[7];
    float* out = (float*)d_out;

    // workspace, no aliasing (61 MB):
    u16*   regA = (u16*)d_ws;                    // avg -> ffn   (16 MB)
    u16*   regB = regA + (size_t)M * D;          // h            (16 MB)
    u16*   iQb  = regB + (size_t)M * D;          // iQ bf16      (16 MB)
    u16*   W1t  = iQb  + (size_t)M * D;          //              ( 2 MB)
    u16*   W2t  = W1t  + (size_t)D * D;          //              ( 2 MB)
    u16*   Wgt  = W2t  + (size_t)D * D;          //              ( 8 MB)
    float* csum = (float*)(Wgt + (size_t)D2 * D2); // B*64*D f32 ( 1 MB)

    u16* avg = regA;
    u16* ffn = regA;
    u16* h   = regB;

    // 1. all independent prologue work in one big dispatch (14592 blocks)
    prologue_kernel<<<14592, 256, 0, stream>>>(W1, W1t, W2, W2t, Wg, Wgt,
                                               iQ, iQb, iV, csum);
    // 2. causal cumulative mean
    scan_kernel<<<B * 64, 256, 0, stream>>>(iV, csum, avg);
    // 3. h = relu(avg @ W1 + b1)
    gemm_kernel<0><<<dim3(M / 128, D / 128), 256, 0, stream>>>(avg, W1t, b1, h, M, D, D);
    // 4. ffn = h @ W2 + b2   (overlays avg)
    gemm_kernel<1><<<dim3(M / 128, D / 128), 256, 0, stream>>>(h, W2t, b2, ffn, M, D, D);
    // 5. fused gate GEMM + sigmoid-gate epilogue (8-phase, m201-faithful)
    gate8f_kernel<<<256, 512, 0, stream>>>(iQb, ffn, Wgt, bg, iQ, out);
}

// Round 5
// 268.247 us; speedup vs baseline: 1.1371x; 1.0248x over previous
//
#include <hip/hip_runtime.h>
#include <hip/hip_bf16.h>
#include <cstdint>

typedef unsigned short u16;
typedef unsigned int   u32;

typedef __attribute__((ext_vector_type(8))) short short8;   // 8 x bf16 (4 VGPRs)
typedef __attribute__((ext_vector_type(4))) float f32x4;    // MFMA accumulator

__device__ __forceinline__ float b2f(u16 v) { return __uint_as_float(((u32)v) << 16); }
__device__ __forceinline__ u16 f2b(float f) {
    u32 u = __float_as_uint(f);
    u += 0x7FFFu + ((u >> 16) & 1u);   // round-to-nearest-even
    return (u16)(u >> 16);
}

#define G2L16(gp, lp) __builtin_amdgcn_global_load_lds(                       \
    (const __attribute__((address_space(1))) void*)(gp),                      \
    (__attribute__((address_space(3))) void*)(lp), 16, 0, 0)

// ---------------------------------------------------------------------------
// Fused prologue (one dispatch):
//   blocks [0,1024)      : W1 -> W1t (bf16, transposed)
//   blocks [1024,2048)   : W2 -> W2t
//   blocks [2048,6144)   : Wg -> Wgt
//   blocks [6144,14336)  : cast iQ f32 -> iQb bf16
//   blocks [14336,14848) : chunk sums of iV (128 chunks of 16 rows per batch)
// ---------------------------------------------------------------------------
__device__ __forceinline__ void transpose_body(const float* __restrict__ in,
                                               u16* __restrict__ out,
                                               int R, int C, int lb, int tilesX,
                                               float (*tile)[33]) {
    const int bx = (lb % tilesX) * 32;
    const int by = (lb / tilesX) * 32;
    const int tx = threadIdx.x & 31, ty = threadIdx.x >> 5;   // 32 x 8
    #pragma unroll
    for (int i = 0; i < 32; i += 8)
        tile[ty + i][tx] = in[(size_t)(by + ty + i) * C + (bx + tx)];
    __syncthreads();
    #pragma unroll
    for (int i = 0; i < 32; i += 8)
        out[(size_t)(bx + ty + i) * R + (by + tx)] = f2b(tile[tx][ty + i]);
}

__global__ void prologue_kernel(const float* __restrict__ W1, u16* __restrict__ W1t,
                                const float* __restrict__ W2, u16* __restrict__ W2t,
                                const float* __restrict__ Wg, u16* __restrict__ Wgt,
                                const float* __restrict__ iQ, u16* __restrict__ iQb,
                                const float* __restrict__ iV, float* __restrict__ csum) {
    __shared__ float tile[32][33];
    const int bid = blockIdx.x;
    const int tid = threadIdx.x;
    if (bid < 1024) {
        transpose_body(W1, W1t, 1024, 1024, bid, 32, tile);
    } else if (bid < 2048) {
        transpose_body(W2, W2t, 1024, 1024, bid - 1024, 32, tile);
    } else if (bid < 6144) {
        transpose_body(Wg, Wgt, 2048, 2048, bid - 2048, 64, tile);
    } else if (bid < 14336) {
        const size_t i = ((size_t)(bid - 6144) * 256 + tid) * 4;
        const float4 v = *(const float4*)(iQ + i);
        ushort4 o;
        o.x = f2b(v.x); o.y = f2b(v.y); o.z = f2b(v.z); o.w = f2b(v.w);
        *(ushort4*)(iQb + i) = o;
    } else {
        // chunk sums: 16-row chunks, 128 chunks per batch, 4 batches -> 512 blocks
        const int idx = bid - 14336;
        const int b = idx >> 7, c = idx & 127;
        const int d = tid * 4;                              // D = 1024
        const float* src = iV + ((size_t)(b * 2048 + c * 16)) * 1024 + d;
        float4 s = {0.f, 0.f, 0.f, 0.f};
        #pragma unroll 8
        for (int i = 0; i < 16; ++i) {
            const float4 v = *(const float4*)(src + (size_t)i * 1024);
            s.x += v.x; s.y += v.y; s.z += v.z; s.w += v.w;
        }
        *(float4*)(csum + ((size_t)(b * 128 + c)) * 1024 + d) = s;
    }
}

// ---------------------------------------------------------------------------
// Scan: prefix over chunk sums (4-way ILP) + in-chunk serial scan -> avg bf16.
// 16-row chunks -> 512 blocks (8 waves/CU vs 4 at 32-row chunks).
// ---------------------------------------------------------------------------
__global__ void scan_kernel(const float* __restrict__ iV, const float* __restrict__ csum,
                            u16* __restrict__ avg) {
    const int c = blockIdx.x & 127, b = blockIdx.x >> 7;
    const int d = threadIdx.x * 4;
    const float* cs = csum + (size_t)b * 128 * 1024 + d;
    float4 a0 = {0,0,0,0}, a1 = {0,0,0,0}, a2 = {0,0,0,0}, a3 = {0,0,0,0};
    int cc = 0;
    for (; cc + 4 <= c; cc += 4) {
        const float4 v0 = *(const float4*)(cs + (size_t)(cc + 0) * 1024);
        const float4 v1 = *(const float4*)(cs + (size_t)(cc + 1) * 1024);
        const float4 v2 = *(const float4*)(cs + (size_t)(cc + 2) * 1024);
        const float4 v3 = *(const float4*)(cs + (size_t)(cc + 3) * 1024);
        a0.x += v0.x; a0.y += v0.y; a0.z += v0.z; a0.w += v0.w;
        a1.x += v1.x; a1.y += v1.y; a1.z += v1.z; a1.w += v1.w;
        a2.x += v2.x; a2.y += v2.y; a2.z += v2.z; a2.w += v2.w;
        a3.x += v3.x; a3.y += v3.y; a3.z += v3.z; a3.w += v3.w;
    }
    for (; cc < c; ++cc) {
        const float4 v = *(const float4*)(cs + (size_t)cc * 1024);
        a0.x += v.x; a0.y += v.y; a0.z += v.z; a0.w += v.w;
    }
    float4 acc;
    acc.x = (a0.x + a1.x) + (a2.x + a3.x);
    acc.y = (a0.y + a1.y) + (a2.y + a3.y);
    acc.z = (a0.z + a1.z) + (a2.z + a3.z);
    acc.w = (a0.w + a1.w) + (a2.w + a3.w);

    const size_t off = ((size_t)(b * 2048 + c * 16)) * 1024 + d;
    const float* src = iV + off;
    u16*         dst = avg + off;
    const int s0 = c * 16;
    #pragma unroll 4
    for (int i = 0; i < 16; ++i) {
        const float4 v = *(const float4*)(src + (size_t)i * 1024);
        acc.x += v.x; acc.y += v.y; acc.z += v.z; acc.w += v.w;
        const float inv = 1.0f / (float)(s0 + i + 1);
        ushort4 o;
        o.x = f2b(acc.x * inv); o.y = f2b(acc.y * inv);
        o.z = f2b(acc.z * inv); o.w = f2b(acc.w * inv);
        *(ushort4*)(dst + (size_t)i * 1024) = o;
    }
}

// ---------------------------------------------------------------------------
// Round-0 proven MFMA GEMM (948 TF-class), BK=64, XOR-swizzled LDS
// (conflict-free ds_read_b128). EPI: 0 = relu(x+b), 1 = x+b.
// ---------------------------------------------------------------------------
template <int EPI>
__global__ __launch_bounds__(256, 2)
void gemm_kernel(const u16* __restrict__ A, const u16* __restrict__ Bt,
                 const float* __restrict__ bias, u16* __restrict__ C,
                 int M, int N, int K) {
    __shared__ u16 As[128 * 64];
    __shared__ u16 Bs[128 * 64];

    const int tid  = threadIdx.x;
    const int m0   = blockIdx.x * 128;
    const int n0   = blockIdx.y * 128;
    const int wave = tid >> 6, lane = tid & 63;
    const int wm   = (wave & 1) << 6;
    const int wn   = (wave >> 1) << 6;
    const int quad = lane >> 4, l16 = lane & 15;

    f32x4 acc[4][4];
    #pragma unroll
    for (int i = 0; i < 4; ++i)
        #pragma unroll
        for (int j = 0; j < 4; ++j) acc[i][j] = (f32x4){0.f, 0.f, 0.f, 0.f};

    int oo[4], rr[4], qq[4];
    #pragma unroll
    for (int j = 0; j < 4; ++j) {
        oo[j] = tid * 16 + j * 4096;
        rr[j] = oo[j] >> 7;
        qq[j] = ((oo[j] >> 4) & 7) ^ (rr[j] & 7);
    }

    const int ktiles = K >> 6;
    for (int kt = 0; kt < ktiles; ++kt) {
        const int kb = kt << 6;
        #pragma unroll
        for (int j = 0; j < 4; ++j) {
            G2L16((const char*)A  + ((size_t)(m0 + rr[j]) * K + kb) * 2 + qq[j] * 16,
                  (char*)As + oo[j]);
            G2L16((const char*)Bt + ((size_t)(n0 + rr[j]) * K + kb) * 2 + qq[j] * 16,
                  (char*)Bs + oo[j]);
        }
        __syncthreads();

        #pragma unroll
        for (int h = 0; h < 2; ++h) {
            short8 af[4], bf[4];
            #pragma unroll
            for (int mi = 0; mi < 4; ++mi) {
                const int R = wm + mi * 16 + l16;
                af[mi] = *(const short8*)(As + R * 64 + ((((h << 2) | quad) ^ (R & 7)) << 3));
            }
            #pragma unroll
            for (int ni = 0; ni < 4; ++ni) {
                const int R = wn + ni * 16 + l16;
                bf[ni] = *(const short8*)(Bs + R * 64 + ((((h << 2) | quad) ^ (R & 7)) << 3));
            }
            #pragma unroll
            for (int mi = 0; mi < 4; ++mi)
                #pragma unroll
                for (int ni = 0; ni < 4; ++ni)
                    acc[mi][ni] = __builtin_amdgcn_mfma_f32_16x16x32_bf16(
                        af[mi], bf[ni], acc[mi][ni], 0, 0, 0);
        }
        __syncthreads();
    }

    #pragma unroll
    for (int ni = 0; ni < 4; ++ni) {
        const int col = n0 + wn + ni * 16 + l16;
        const float bv = bias[col];
        #pragma unroll
        for (int mi = 0; mi < 4; ++mi) {
            const int row0 = m0 + wm + mi * 16 + quad * 4;
            #pragma unroll
            for (int r = 0; r < 4; ++r) {
                float v = acc[mi][ni][r] + bv;
                if (EPI == 0) v = fmaxf(v, 0.f);
                C[(size_t)(row0 + r) * N + col] = f2b(v);
            }
        }
    }
}

// ---------------------------------------------------------------------------
// Round-0 proven fused GEMM3 + sigmoid + gate, BK=64 + swizzled LDS.
// out = gi*iQ + gf*ffn (f32), gi/gf = sigmoid(concat(iQ,ffn)@Wg[:,col/col+D]+bg)
// ---------------------------------------------------------------------------
__global__ __launch_bounds__(256, 2)
void gemm_gate_kernel(const u16* __restrict__ iQb, const u16* __restrict__ ffn,
                      const u16* __restrict__ Wgt, const float* __restrict__ bg,
                      const float* __restrict__ iQ, float* __restrict__ out,
                      int M, int D2 /*2048*/) {
    __shared__ u16 As [128 * 64];
    __shared__ u16 Bs0[128 * 64];
    __shared__ u16 Bs1[128 * 64];

    const int tid  = threadIdx.x;
    const int m0   = blockIdx.x * 128;
    const int n0   = blockIdx.y * 128;          // out-col tile, n0 < 1024
    const int wave = tid >> 6, lane = tid & 63;
    const int wm   = (wave & 1) << 6;
    const int wn   = (wave >> 1) << 6;
    const int quad = lane >> 4, l16 = lane & 15;
    const int D = D2 >> 1;                      // 1024

    f32x4 acc[2][4][4];
    #pragma unroll
    for (int p = 0; p < 2; ++p)
        #pragma unroll
        for (int i = 0; i < 4; ++i)
            #pragma unroll
            for (int j = 0; j < 4; ++j) acc[p][i][j] = (f32x4){0.f, 0.f, 0.f, 0.f};

    int oo[4], rr[4], qq[4];
    #pragma unroll
    for (int j = 0; j < 4; ++j) {
        oo[j] = tid * 16 + j * 4096;
        rr[j] = oo[j] >> 7;
        qq[j] = ((oo[j] >> 4) & 7) ^ (rr[j] & 7);
    }

    const int ktiles = D2 >> 6;                 // 32
    for (int kt = 0; kt < ktiles; ++kt) {
        const int kb = kt << 6;
        const char* Ab = (const char*)((kb < D) ? (iQb + kb) : (ffn + (kb - D)));
        const char* B0 = (const char*)(Wgt + (size_t)n0 * D2 + kb);
        const char* B1 = (const char*)(Wgt + (size_t)(n0 + D) * D2 + kb);
        #pragma unroll
        for (int j = 0; j < 4; ++j) {
            G2L16(Ab + (size_t)(m0 + rr[j]) * D * 2 + qq[j] * 16, (char*)As  + oo[j]);
            G2L16(B0 + (size_t)rr[j] * D2 * 2 + qq[j] * 16,       (char*)Bs0 + oo[j]);
            G2L16(B1 + (size_t)rr[j] * D2 * 2 + qq[j] * 16,       (char*)Bs1 + oo[j]);
        }
        __syncthreads();

        #pragma unroll
        for (int h = 0; h < 2; ++h) {
            short8 af[4], bf0[4], bf1[4];
            #pragma unroll
            for (int mi = 0; mi < 4; ++mi) {
                const int R = wm + mi * 16 + l16;
                af[mi] = *(const short8*)(As + R * 64 + ((((h << 2) | quad) ^ (R & 7)) << 3));
            }
            #pragma unroll
            for (int ni = 0; ni < 4; ++ni) {
                const int R = wn + ni * 16 + l16;
                const int so = R * 64 + ((((h << 2) | quad) ^ (R & 7)) << 3);
                bf0[ni] = *(const short8*)(Bs0 + so);
                bf1[ni] = *(const short8*)(Bs1 + so);
            }
            #pragma unroll
            for (int mi = 0; mi < 4; ++mi)
                #pragma unroll
                for (int ni = 0; ni < 4; ++ni) {
                    acc[0][mi][ni] = __builtin_amdgcn_mfma_f32_16x16x32_bf16(
                        af[mi], bf0[ni], acc[0][mi][ni], 0, 0, 0);
                    acc[1][mi][ni] = __builtin_amdgcn_mfma_f32_16x16x32_bf16(
                        af[mi], bf1[ni], acc[1][mi][ni], 0, 0, 0);
                }
        }
        __syncthreads();
    }

    #pragma unroll
    for (int ni = 0; ni < 4; ++ni) {
        const int col = n0 + wn + ni * 16 + l16;
        const float bgi = bg[col];
        const float bgf = bg[col + D];
        #pragma unroll
        for (int mi = 0; mi < 4; ++mi) {
            const int row0 = m0 + wm + mi * 16 + quad * 4;
            #pragma unroll
            for (int r = 0; r < 4; ++r) {
                const size_t idx = (size_t)(row0 + r) * D + col;
                const float gi = 1.0f / (1.0f + __expf(-(acc[0][mi][ni][r] + bgi)));
                const float gf = 1.0f / (1.0f + __expf(-(acc[1][mi][ni][r] + bgf)));
                out[idx] = gi * iQ[idx] + gf * b2f(ffn[idx]);
            }
        }
    }
}

// ---------------------------------------------------------------------------
extern "C" void kernel_launch(void* const* d_in, const int* in_sizes, int n_in,
                              void* d_out, int out_size, void* d_ws, size_t ws_size,
                              hipStream_t stream) {
    const int B = 4, S = 2048, D = 1024, D2 = 2048;
    const int M = B * S;  // 8192

    const float* iQ = (const float*)d_in[0];
    const float* iV = (const float*)d_in[1];
    const float* W1 = (const float*)d_in[2];
    const float* b1 = (const float*)d_in[3];
    const float* W2 = (const float*)d_in[4];
    const float* b2 = (const float*)d_in[5];
    const float* Wg = (const float*)d_in[6];
    const float* bg = (const float*)d_in[7];
    float* out = (float*)d_out;

    // workspace, no aliasing (62 MB):
    u16*   regA = (u16*)d_ws;                    // avg -> ffn   (16 MB)
    u16*   regB = regA + (size_t)M * D;          // h            (16 MB)
    u16*   iQb  = regB + (size_t)M * D;          // iQ bf16      (16 MB)
    u16*   W1t  = iQb  + (size_t)M * D;          //              ( 2 MB)
    u16*   W2t  = W1t  + (size_t)D * D;          //              ( 2 MB)
    u16*   Wgt  = W2t  + (size_t)D * D;          //              ( 8 MB)
    float* csum = (float*)(Wgt + (size_t)D2 * D2); // B*128*D f32 ( 2 MB)

    u16* avg = regA;
    u16* ffn = regA;
    u16* h   = regB;

    // 1. all independent prologue work in one big dispatch (14848 blocks)
    prologue_kernel<<<14848, 256, 0, stream>>>(W1, W1t, W2, W2t, Wg, Wgt,
                                               iQ, iQb, iV, csum);
    // 2. causal cumulative mean (16-row chunks, 512 blocks)
    scan_kernel<<<B * 128, 256, 0, stream>>>(iV, csum, avg);
    // 3. h = relu(avg @ W1 + b1)
    gemm_kernel<0><<<dim3(M / 128, D / 128), 256, 0, stream>>>(avg, W1t, b1, h, M, D, D);
    // 4. ffn = h @ W2 + b2   (overlays avg)
    gemm_kernel<1><<<dim3(M / 128, D / 128), 256, 0, stream>>>(h, W2t, b2, ffn, M, D, D);
    // 5. fused gate GEMM + sigmoid-gate epilogue
    gemm_gate_kernel<<<dim3(M / 128, D / 128), 256, 0, stream>>>(
        iQb, ffn, Wgt, bg, iQ, out, M, D2);
}

// Round 6
// 262.143 us; speedup vs baseline: 1.1636x; 1.0233x over previous
//
#include <hip/hip_runtime.h>
#include <hip/hip_bf16.h>
#include <cstdint>

typedef unsigned short u16;
typedef unsigned int   u32;

typedef __attribute__((ext_vector_type(8))) short short8;   // 8 x bf16 (4 VGPRs)
typedef __attribute__((ext_vector_type(4))) float f32x4;    // MFMA accumulator

__device__ __forceinline__ float b2f(u16 v) { return __uint_as_float(((u32)v) << 16); }
__device__ __forceinline__ u16 f2b(float f) {
    u32 u = __float_as_uint(f);
    u += 0x7FFFu + ((u >> 16) & 1u);   // round-to-nearest-even
    return (u16)(u >> 16);
}

#define G2L16(gp, lp) __builtin_amdgcn_global_load_lds(                       \
    (const __attribute__((address_space(1))) void*)(gp),                      \
    (__attribute__((address_space(3))) void*)(lp), 16, 0, 0)

// ---------------------------------------------------------------------------
// Fused prologue (one dispatch):
//   blocks [0,1024)      : W1 -> W1t (bf16, transposed)
//   blocks [1024,2048)   : W2 -> W2t
//   blocks [2048,6144)   : Wg -> Wgt
//   blocks [6144,14336)  : cast iQ f32 -> iQb bf16
//   blocks [14336,14848) : chunk sums of iV (128 chunks of 16 rows per batch)
// ---------------------------------------------------------------------------
__device__ __forceinline__ void transpose_body(const float* __restrict__ in,
                                               u16* __restrict__ out,
                                               int R, int C, int lb, int tilesX,
                                               float (*tile)[33]) {
    const int bx = (lb % tilesX) * 32;
    const int by = (lb / tilesX) * 32;
    const int tx = threadIdx.x & 31, ty = threadIdx.x >> 5;   // 32 x 8
    #pragma unroll
    for (int i = 0; i < 32; i += 8)
        tile[ty + i][tx] = in[(size_t)(by + ty + i) * C + (bx + tx)];
    __syncthreads();
    #pragma unroll
    for (int i = 0; i < 32; i += 8)
        out[(size_t)(bx + ty + i) * R + (by + tx)] = f2b(tile[tx][ty + i]);
}

__global__ void prologue_kernel(const float* __restrict__ W1, u16* __restrict__ W1t,
                                const float* __restrict__ W2, u16* __restrict__ W2t,
                                const float* __restrict__ Wg, u16* __restrict__ Wgt,
                                const float* __restrict__ iQ, u16* __restrict__ iQb,
                                const float* __restrict__ iV, float* __restrict__ csum) {
    __shared__ float tile[32][33];
    const int bid = blockIdx.x;
    const int tid = threadIdx.x;
    if (bid < 1024) {
        transpose_body(W1, W1t, 1024, 1024, bid, 32, tile);
    } else if (bid < 2048) {
        transpose_body(W2, W2t, 1024, 1024, bid - 1024, 32, tile);
    } else if (bid < 6144) {
        transpose_body(Wg, Wgt, 2048, 2048, bid - 2048, 64, tile);
    } else if (bid < 14336) {
        const size_t i = ((size_t)(bid - 6144) * 256 + tid) * 4;
        const float4 v = *(const float4*)(iQ + i);
        ushort4 o;
        o.x = f2b(v.x); o.y = f2b(v.y); o.z = f2b(v.z); o.w = f2b(v.w);
        *(ushort4*)(iQb + i) = o;
    } else {
        // chunk sums: 16-row chunks, 128 chunks per batch, 4 batches -> 512 blocks
        const int idx = bid - 14336;
        const int b = idx >> 7, c = idx & 127;
        const int d = tid * 4;                              // D = 1024
        const float* src = iV + ((size_t)(b * 2048 + c * 16)) * 1024 + d;
        float4 s = {0.f, 0.f, 0.f, 0.f};
        #pragma unroll 8
        for (int i = 0; i < 16; ++i) {
            const float4 v = *(const float4*)(src + (size_t)i * 1024);
            s.x += v.x; s.y += v.y; s.z += v.z; s.w += v.w;
        }
        *(float4*)(csum + ((size_t)(b * 128 + c)) * 1024 + d) = s;
    }
}

// ---------------------------------------------------------------------------
// Scan: prefix over chunk sums (4-way ILP) + in-chunk serial scan -> avg bf16.
// 16-row chunks -> 512 blocks (8 waves/CU).
// ---------------------------------------------------------------------------
__global__ void scan_kernel(const float* __restrict__ iV, const float* __restrict__ csum,
                            u16* __restrict__ avg) {
    const int c = blockIdx.x & 127, b = blockIdx.x >> 7;
    const int d = threadIdx.x * 4;
    const float* cs = csum + (size_t)b * 128 * 1024 + d;
    float4 a0 = {0,0,0,0}, a1 = {0,0,0,0}, a2 = {0,0,0,0}, a3 = {0,0,0,0};
    int cc = 0;
    for (; cc + 4 <= c; cc += 4) {
        const float4 v0 = *(const float4*)(cs + (size_t)(cc + 0) * 1024);
        const float4 v1 = *(const float4*)(cs + (size_t)(cc + 1) * 1024);
        const float4 v2 = *(const float4*)(cs + (size_t)(cc + 2) * 1024);
        const float4 v3 = *(const float4*)(cs + (size_t)(cc + 3) * 1024);
        a0.x += v0.x; a0.y += v0.y; a0.z += v0.z; a0.w += v0.w;
        a1.x += v1.x; a1.y += v1.y; a1.z += v1.z; a1.w += v1.w;
        a2.x += v2.x; a2.y += v2.y; a2.z += v2.z; a2.w += v2.w;
        a3.x += v3.x; a3.y += v3.y; a3.z += v3.z; a3.w += v3.w;
    }
    for (; cc < c; ++cc) {
        const float4 v = *(const float4*)(cs + (size_t)cc * 1024);
        a0.x += v.x; a0.y += v.y; a0.z += v.z; a0.w += v.w;
    }
    float4 acc;
    acc.x = (a0.x + a1.x) + (a2.x + a3.x);
    acc.y = (a0.y + a1.y) + (a2.y + a3.y);
    acc.z = (a0.z + a1.z) + (a2.z + a3.z);
    acc.w = (a0.w + a1.w) + (a2.w + a3.w);

    const size_t off = ((size_t)(b * 2048 + c * 16)) * 1024 + d;
    const float* src = iV + off;
    u16*         dst = avg + off;
    const int s0 = c * 16;
    #pragma unroll 4
    for (int i = 0; i < 16; ++i) {
        const float4 v = *(const float4*)(src + (size_t)i * 1024);
        acc.x += v.x; acc.y += v.y; acc.z += v.z; acc.w += v.w;
        const float inv = 1.0f / (float)(s0 + i + 1);
        ushort4 o;
        o.x = f2b(acc.x * inv); o.y = f2b(acc.y * inv);
        o.z = f2b(acc.z * inv); o.w = f2b(acc.w * inv);
        *(ushort4*)(dst + (size_t)i * 1024) = o;
    }
}

// ---------------------------------------------------------------------------
// MFMA GEMM, BK=128 as two adjacent BK=64 sub-tiles per barrier window
// (identical proven swizzle per sub-tile; 64 MFMA/wave per window, 8 windows
// at K=1024 vs 16 -> barrier-drain amortized 2x). LDS 64KB -> 2 blocks/CU.
// EPI: 0 = relu(x+b), 1 = x+b.
// ---------------------------------------------------------------------------
template <int EPI>
__global__ __launch_bounds__(256, 2)
void gemm_kernel(const u16* __restrict__ A, const u16* __restrict__ Bt,
                 const float* __restrict__ bias, u16* __restrict__ C,
                 int M, int N, int K) {
    __shared__ u16 As[2][128 * 64];
    __shared__ u16 Bs[2][128 * 64];

    const int tid  = threadIdx.x;
    const int m0   = blockIdx.x * 128;
    const int n0   = blockIdx.y * 128;
    const int wave = tid >> 6, lane = tid & 63;
    const int wm   = (wave & 1) << 6;
    const int wn   = (wave >> 1) << 6;
    const int quad = lane >> 4, l16 = lane & 15;

    f32x4 acc[4][4];
    #pragma unroll
    for (int i = 0; i < 4; ++i)
        #pragma unroll
        for (int j = 0; j < 4; ++j) acc[i][j] = (f32x4){0.f, 0.f, 0.f, 0.f};

    int oo[4], rr[4], qq[4];
    #pragma unroll
    for (int j = 0; j < 4; ++j) {
        oo[j] = tid * 16 + j * 4096;
        rr[j] = oo[j] >> 7;
        qq[j] = ((oo[j] >> 4) & 7) ^ (rr[j] & 7);
    }

    const int ktiles = K >> 7;                  // BK=128 -> 8 windows
    for (int kt = 0; kt < ktiles; ++kt) {
        const int kb = kt << 7;
        #pragma unroll
        for (int kk = 0; kk < 2; ++kk) {
            const int kbk = kb + kk * 64;
            #pragma unroll
            for (int j = 0; j < 4; ++j) {
                G2L16((const char*)A  + ((size_t)(m0 + rr[j]) * K + kbk) * 2 + qq[j] * 16,
                      (char*)&As[kk][0] + oo[j]);
                G2L16((const char*)Bt + ((size_t)(n0 + rr[j]) * K + kbk) * 2 + qq[j] * 16,
                      (char*)&Bs[kk][0] + oo[j]);
            }
        }
        __syncthreads();

        #pragma unroll
        for (int kk = 0; kk < 2; ++kk) {
            #pragma unroll
            for (int h = 0; h < 2; ++h) {
                short8 af[4], bf[4];
                #pragma unroll
                for (int mi = 0; mi < 4; ++mi) {
                    const int R = wm + mi * 16 + l16;
                    af[mi] = *(const short8*)(&As[kk][0] + R * 64 +
                                              ((((h << 2) | quad) ^ (R & 7)) << 3));
                }
                #pragma unroll
                for (int ni = 0; ni < 4; ++ni) {
                    const int R = wn + ni * 16 + l16;
                    bf[ni] = *(const short8*)(&Bs[kk][0] + R * 64 +
                                              ((((h << 2) | quad) ^ (R & 7)) << 3));
                }
                #pragma unroll
                for (int mi = 0; mi < 4; ++mi)
                    #pragma unroll
                    for (int ni = 0; ni < 4; ++ni)
                        acc[mi][ni] = __builtin_amdgcn_mfma_f32_16x16x32_bf16(
                            af[mi], bf[ni], acc[mi][ni], 0, 0, 0);
            }
        }
        __syncthreads();
    }

    #pragma unroll
    for (int ni = 0; ni < 4; ++ni) {
        const int col = n0 + wn + ni * 16 + l16;
        const float bv = bias[col];
        #pragma unroll
        for (int mi = 0; mi < 4; ++mi) {
            const int row0 = m0 + wm + mi * 16 + quad * 4;
            #pragma unroll
            for (int r = 0; r < 4; ++r) {
                float v = acc[mi][ni][r] + bv;
                if (EPI == 0) v = fmaxf(v, 0.f);
                C[(size_t)(row0 + r) * N + col] = f2b(v);
            }
        }
    }
}

// ---------------------------------------------------------------------------
// Round-0 proven fused GEMM3 + sigmoid + gate, BK=64 + swizzled LDS.
// out = gi*iQ + gf*ffn (f32), gi/gf = sigmoid(concat(iQ,ffn)@Wg[:,col/col+D]+bg)
// ---------------------------------------------------------------------------
__global__ __launch_bounds__(256, 2)
void gemm_gate_kernel(const u16* __restrict__ iQb, const u16* __restrict__ ffn,
                      const u16* __restrict__ Wgt, const float* __restrict__ bg,
                      const float* __restrict__ iQ, float* __restrict__ out,
                      int M, int D2 /*2048*/) {
    __shared__ u16 As [128 * 64];
    __shared__ u16 Bs0[128 * 64];
    __shared__ u16 Bs1[128 * 64];

    const int tid  = threadIdx.x;
    const int m0   = blockIdx.x * 128;
    const int n0   = blockIdx.y * 128;          // out-col tile, n0 < 1024
    const int wave = tid >> 6, lane = tid & 63;
    const int wm   = (wave & 1) << 6;
    const int wn   = (wave >> 1) << 6;
    const int quad = lane >> 4, l16 = lane & 15;
    const int D = D2 >> 1;                      // 1024

    f32x4 acc[2][4][4];
    #pragma unroll
    for (int p = 0; p < 2; ++p)
        #pragma unroll
        for (int i = 0; i < 4; ++i)
            #pragma unroll
            for (int j = 0; j < 4; ++j) acc[p][i][j] = (f32x4){0.f, 0.f, 0.f, 0.f};

    int oo[4], rr[4], qq[4];
    #pragma unroll
    for (int j = 0; j < 4; ++j) {
        oo[j] = tid * 16 + j * 4096;
        rr[j] = oo[j] >> 7;
        qq[j] = ((oo[j] >> 4) & 7) ^ (rr[j] & 7);
    }

    const int ktiles = D2 >> 6;                 // 32
    for (int kt = 0; kt < ktiles; ++kt) {
        const int kb = kt << 6;
        const char* Ab = (const char*)((kb < D) ? (iQb + kb) : (ffn + (kb - D)));
        const char* B0 = (const char*)(Wgt + (size_t)n0 * D2 + kb);
        const char* B1 = (const char*)(Wgt + (size_t)(n0 + D) * D2 + kb);
        #pragma unroll
        for (int j = 0; j < 4; ++j) {
            G2L16(Ab + (size_t)(m0 + rr[j]) * D * 2 + qq[j] * 16, (char*)As  + oo[j]);
            G2L16(B0 + (size_t)rr[j] * D2 * 2 + qq[j] * 16,       (char*)Bs0 + oo[j]);
            G2L16(B1 + (size_t)rr[j] * D2 * 2 + qq[j] * 16,       (char*)Bs1 + oo[j]);
        }
        __syncthreads();

        #pragma unroll
        for (int h = 0; h < 2; ++h) {
            short8 af[4], bf0[4], bf1[4];
            #pragma unroll
            for (int mi = 0; mi < 4; ++mi) {
                const int R = wm + mi * 16 + l16;
                af[mi] = *(const short8*)(As + R * 64 + ((((h << 2) | quad) ^ (R & 7)) << 3));
            }
            #pragma unroll
            for (int ni = 0; ni < 4; ++ni) {
                const int R = wn + ni * 16 + l16;
                const int so = R * 64 + ((((h << 2) | quad) ^ (R & 7)) << 3);
                bf0[ni] = *(const short8*)(Bs0 + so);
                bf1[ni] = *(const short8*)(Bs1 + so);
            }
            #pragma unroll
            for (int mi = 0; mi < 4; ++mi)
                #pragma unroll
                for (int ni = 0; ni < 4; ++ni) {
                    acc[0][mi][ni] = __builtin_amdgcn_mfma_f32_16x16x32_bf16(
                        af[mi], bf0[ni], acc[0][mi][ni], 0, 0, 0);
                    acc[1][mi][ni] = __builtin_amdgcn_mfma_f32_16x16x32_bf16(
                        af[mi], bf1[ni], acc[1][mi][ni], 0, 0, 0);
                }
        }
        __syncthreads();
    }

    #pragma unroll
    for (int ni = 0; ni < 4; ++ni) {
        const int col = n0 + wn + ni * 16 + l16;
        const float bgi = bg[col];
        const float bgf = bg[col + D];
        #pragma unroll
        for (int mi = 0; mi < 4; ++mi) {
            const int row0 = m0 + wm + mi * 16 + quad * 4;
            #pragma unroll
            for (int r = 0; r < 4; ++r) {
                const size_t idx = (size_t)(row0 + r) * D + col;
                const float gi = 1.0f / (1.0f + __expf(-(acc[0][mi][ni][r] + bgi)));
                const float gf = 1.0f / (1.0f + __expf(-(acc[1][mi][ni][r] + bgf)));
                out[idx] = gi * iQ[idx] + gf * b2f(ffn[idx]);
            }
        }
    }
}

// ---------------------------------------------------------------------------
extern "C" void kernel_launch(void* const* d_in, const int* in_sizes, int n_in,
                              void* d_out, int out_size, void* d_ws, size_t ws_size,
                              hipStream_t stream) {
    const int B = 4, S = 2048, D = 1024, D2 = 2048;
    const int M = B * S;  // 8192

    const float* iQ = (const float*)d_in[0];
    const float* iV = (const float*)d_in[1];
    const float* W1 = (const float*)d_in[2];
    const float* b1 = (const float*)d_in[3];
    const float* W2 = (const float*)d_in[4];
    const float* b2 = (const float*)d_in[5];
    const float* Wg = (const float*)d_in[6];
    const float* bg = (const float*)d_in[7];
    float* out = (float*)d_out;

    // workspace, no aliasing (62 MB):
    u16*   regA = (u16*)d_ws;                    // avg -> ffn   (16 MB)
    u16*   regB = regA + (size_t)M * D;          // h            (16 MB)
    u16*   iQb  = regB + (size_t)M * D;          // iQ bf16      (16 MB)
    u16*   W1t  = iQb  + (size_t)M * D;          //              ( 2 MB)
    u16*   W2t  = W1t  + (size_t)D * D;          //              ( 2 MB)
    u16*   Wgt  = W2t  + (size_t)D * D;          //              ( 8 MB)
    float* csum = (float*)(Wgt + (size_t)D2 * D2); // B*128*D f32 ( 2 MB)

    u16* avg = regA;
    u16* ffn = regA;
    u16* h   = regB;

    // 1. all independent prologue work in one big dispatch (14848 blocks)
    prologue_kernel<<<14848, 256, 0, stream>>>(W1, W1t, W2, W2t, Wg, Wgt,
                                               iQ, iQb, iV, csum);
    // 2. causal cumulative mean (16-row chunks, 512 blocks)
    scan_kernel<<<B * 128, 256, 0, stream>>>(iV, csum, avg);
    // 3. h = relu(avg @ W1 + b1)   (BK=128 windows)
    gemm_kernel<0><<<dim3(M / 128, D / 128), 256, 0, stream>>>(avg, W1t, b1, h, M, D, D);
    // 4. ffn = h @ W2 + b2   (overlays avg)
    gemm_kernel<1><<<dim3(M / 128, D / 128), 256, 0, stream>>>(h, W2t, b2, ffn, M, D, D);
    // 5. fused gate GEMM + sigmoid-gate epilogue
    gemm_gate_kernel<<<dim3(M / 128, D / 128), 256, 0, stream>>>(
        iQb, ffn, Wgt, bg, iQ, out, M, D2);
}